// Round 2
// baseline (275.176 us; speedup 1.0000x reference)
//
#include <hip/hip_runtime.h>
#include <hip/hip_bf16.h>
#include <hip/hip_fp16.h>
#include <stdint.h>
#include <math.h>

// ---------------------------------------------------------------------------
// AttentionLayer: Q=XWq+bq, K=XWk+bk, V=XWv+bv; O = softmax(QK^T) V
// B=4, N=2048, D=1024. fp32 I/O; internals fp16, accumulation fp32.
// R8 (= R7 resubmission; R7 bench died infra-side with no diagnostics):
// QKV and QK^T GEMMs on the 256x256 8-phase schedule (T2+T3+T4+T5):
//  - 512 thr / 8 waves (2Mx4N), BK=64, 128KB LDS = 2 K-tile double buffer
//  - per phase: ds_read quadrant frags | stage 1 half-tile (global_load_lds)
//    | s_barrier | setprio(1) 16xMFMA setprio(0) | s_barrier
//  - counted s_waitcnt vmcnt(6) at phases 4/8 only (3 half-tiles in flight)
//  - half-tile = quadrant row-set (A: bit6, B: bit5) so each region's last
//    ds_read is one phase before its restage (no WAR race)
//  - XOR swizzle chunk^=(row&7) pre-applied on global src, applied on ds_read
// PV / reduce kernels unchanged this round (PV tile shape revisit next).
// ---------------------------------------------------------------------------

typedef unsigned short ushort_t;
typedef __attribute__((ext_vector_type(8))) _Float16  f16x8;
typedef __attribute__((ext_vector_type(4))) _Float16  f16x4;
typedef __attribute__((ext_vector_type(4))) float     f32x4;

__device__ __forceinline__ void async_load16(const void* g, void* l) {
  __builtin_amdgcn_global_load_lds(
      (const __attribute__((address_space(1))) void*)g,
      (__attribute__((address_space(3))) void*)l, 16, 0, 0);
}

// ---------------------------------------------------------------------------
// 256x256 8-phase GEMM core, K=1024, row-major A [256][1024] panel, B^T panel
// [256][1024]. LDS (ushort units): A0 @0, B0 @16384, A1 @32768, B1 @49152.
// ---------------------------------------------------------------------------
#define A0OFF 0
#define B0OFF 16384
#define A1OFF 32768
#define B1OFF 49152

// Stage one quadrant-half (128 rows x 64 f16 = 16KB) of a K-tile.
// SHIFT=6 for A (halves = rows {0-63,128-191} / {64-127,192-255}),
// SHIFT=5 for B (halves = 32-row interleave, matching qn quadrants).
// Global source chunk is pre-swizzled: LDS slot s of row r holds chunk s^(r&7).
// Per-lane LDS addr == wave-uniform base + lane*16B (hardware-linear).
template<int SHIFT>
__device__ __forceinline__ void stage_half(const ushort_t* __restrict__ gb,
                                           int k0, int q, ushort_t* lt, int t)
{
#pragma unroll
  for (int j = 0; j < 2; ++j) {
    const int i   = j * 64 + (t >> 3);
    const int row = ((i >> SHIFT) << (SHIFT + 1)) | (q << SHIFT) | (i & ((1 << SHIFT) - 1));
    const int ch  = (t & 7) ^ (row & 7);
    async_load16(gb + (long)row * 1024 + k0 + ch * 8, lt + row * 64 + (t & 7) * 8);
  }
}

#define BARR do { __builtin_amdgcn_sched_barrier(0); \
                  __builtin_amdgcn_s_barrier();      \
                  __builtin_amdgcn_sched_barrier(0); } while (0)

#define RD_A(TP, QM)                                                          \
  do { _Pragma("unroll") for (int m_ = 0; m_ < 4; ++m_) {                     \
    af[m_][0] = *(const f16x8*)&(TP)[(arow0 + (QM)*64 + m_*16) * 64 + ck0];   \
    af[m_][1] = *(const f16x8*)&(TP)[(arow0 + (QM)*64 + m_*16) * 64 + ck1];   \
  } } while (0)

#define RD_B(TP, QN)                                                          \
  do { _Pragma("unroll") for (int n_ = 0; n_ < 2; ++n_) {                     \
    bf[n_][0] = *(const f16x8*)&(TP)[(brow0 + (QN)*32 + n_*16) * 64 + ck0];   \
    bf[n_][1] = *(const f16x8*)&(TP)[(brow0 + (QN)*32 + n_*16) * 64 + ck1];   \
  } } while (0)

#define MM(QM, QN)                                                            \
  do { __builtin_amdgcn_s_setprio(1);                                         \
  _Pragma("unroll") for (int kh_ = 0; kh_ < 2; ++kh_)                         \
    _Pragma("unroll") for (int m_ = 0; m_ < 4; ++m_)                          \
      _Pragma("unroll") for (int n_ = 0; n_ < 2; ++n_)                        \
        acc[(QM)*4+m_][(QN)*2+n_] = __builtin_amdgcn_mfma_f32_16x16x32_f16(   \
            af[m_][kh_], bf[n_][kh_], acc[(QM)*4+m_][(QN)*2+n_], 0, 0, 0);    \
  __builtin_amdgcn_s_setprio(0); } while (0)

// One iteration = 2 K-tiles (a=ka in bufs0, b=ka+64 in bufs1), 8 phases.
// Stages: ph1: b.B0->B1 | ph2: c.A0->A0 | ph3: c.B1->B0 | ph4: c.A1->A0
//         ph5: c.B0->B0 | ph6: d.A0->A1 | ph7: d.B1->B1 | ph8: d.A1->A1
// (c=ka+128, d=ka+192). vmcnt(6) at ph4/ph8 leaves the 3 newest half-tiles
// in flight; everything older (incl. the tile read next) has landed.
template<bool LAST>
__device__ __forceinline__ void iter256(const ushort_t* __restrict__ Ab,
                                        const ushort_t* __restrict__ Bb,
                                        ushort_t* lds, f32x4 (&acc)[8][4],
                                        int ka, int t, int arow0, int brow0,
                                        int ck0, int ck1)
{
  const int kb = ka + 64, kc = ka + 128, kd = ka + 192;
  f16x8 af[4][2], bf[2][2];

  // ---- tile a (bufs 0) ----
  RD_A(lds + A0OFF, 0); RD_B(lds + B0OFF, 0);
  stage_half<5>(Bb, kb, 0, lds + B1OFF, t);
  BARR; MM(0, 0); BARR;

  RD_B(lds + B0OFF, 1);
  if constexpr (!LAST) stage_half<6>(Ab, kc, 0, lds + A0OFF, t);
  BARR; MM(0, 1); BARR;

  RD_A(lds + A0OFF, 1);
  if constexpr (!LAST) stage_half<5>(Bb, kc, 1, lds + B0OFF, t);
  BARR; MM(1, 1); BARR;

  RD_B(lds + B0OFF, 0);
  if constexpr (!LAST) stage_half<6>(Ab, kc, 1, lds + A0OFF, t);
  BARR; MM(1, 0);
  if constexpr (LAST) asm volatile("s_waitcnt vmcnt(0)" ::: "memory");
  else                asm volatile("s_waitcnt vmcnt(6)" ::: "memory");
  BARR;

  // ---- tile b (bufs 1) ----
  RD_A(lds + A1OFF, 0); RD_B(lds + B1OFF, 0);
  if constexpr (!LAST) stage_half<5>(Bb, kc, 0, lds + B0OFF, t);
  BARR; MM(0, 0); BARR;

  RD_B(lds + B1OFF, 1);
  if constexpr (!LAST) stage_half<6>(Ab, kd, 0, lds + A1OFF, t);
  BARR; MM(0, 1); BARR;

  RD_A(lds + A1OFF, 1);
  if constexpr (!LAST) stage_half<5>(Bb, kd, 1, lds + B1OFF, t);
  BARR; MM(1, 1); BARR;

  RD_B(lds + B1OFF, 0);
  if constexpr (!LAST) stage_half<6>(Ab, kd, 1, lds + A1OFF, t);
  BARR; MM(1, 0);
  if constexpr (!LAST) asm volatile("s_waitcnt vmcnt(6)" ::: "memory");
  BARR;
}

__device__ __forceinline__ void gemm256(const ushort_t* __restrict__ Ab,
                                        const ushort_t* __restrict__ Bb,
                                        ushort_t* lds, f32x4 (&acc)[8][4])
{
  const int t    = threadIdx.x;
  const int lane = t & 63;
  const int wave = t >> 6;
  const int wr   = wave >> 2;        // 0..1 (M)
  const int wc   = wave & 3;         // 0..3 (N)
  const int arow0 = wr * 128 + (lane & 15);
  const int brow0 = wc * 64  + (lane & 15);
  const int ck0 = (((lane >> 4)    ) ^ (lane & 7)) * 8;   // kh=0 chunk (swz)
  const int ck1 = ((4 + (lane >> 4)) ^ (lane & 7)) * 8;   // kh=1 chunk (swz)

  // prologue: t0 fully, t1 {A0,B1,A1}; B0 of t1 staged in iter0-ph1
  stage_half<6>(Ab,  0, 0, lds + A0OFF, t);
  stage_half<5>(Bb,  0, 1, lds + B0OFF, t);
  stage_half<6>(Ab,  0, 1, lds + A0OFF, t);
  stage_half<5>(Bb,  0, 0, lds + B0OFF, t);
  stage_half<6>(Ab, 64, 0, lds + A1OFF, t);
  stage_half<5>(Bb, 64, 1, lds + B1OFF, t);
  stage_half<6>(Ab, 64, 1, lds + A1OFF, t);
  asm volatile("s_waitcnt vmcnt(6)" ::: "memory");
  BARR;

#pragma unroll 1
  for (int it = 0; it < 7; ++it)
    iter256<false>(Ab, Bb, lds, acc, it * 128, t, arow0, brow0, ck0, ck1);
  iter256<true>(Ab, Bb, lds, acc, 896, t, arow0, brow0, ck0, ck1);
}

// ---------------------------------------------------------------------------
// Fused QKV projection on the 8-phase core. A = Xh [8192][1024],
// BT = Wt [3072][1024] (Wq^T|Wk^T|Wv^T). grid (12, M/256). XCD-swizzled.
// ---------------------------------------------------------------------------
__global__ __launch_bounds__(512, 2)
void qkv256_kernel(const ushort_t* __restrict__ A, const ushort_t* __restrict__ BT,
                   const float* __restrict__ bq, const float* __restrict__ bk,
                   const float* __restrict__ bvp,
                   __half* __restrict__ Qh, __half* __restrict__ Kh,
                   ushort_t* __restrict__ Vt)
{
  __shared__ __align__(16) ushort_t lds[65536];   // 128 KB

  const int nb = gridDim.x * gridDim.y;           // multiple of 8
  int id = blockIdx.y * gridDim.x + blockIdx.x;
  id = (id & 7) * (nb >> 3) + (id >> 3);          // bijective XCD swizzle
  const int bx = id % gridDim.x;                  // 0..11
  const int by = id / gridDim.x;

  const ushort_t* Ab = A  + (long)by * 256 * 1024;
  const ushort_t* Bb = BT + (long)bx * 256 * 1024;

  f32x4 acc[8][4];
  const f32x4 zero = {0.0f, 0.0f, 0.0f, 0.0f};
#pragma unroll
  for (int i = 0; i < 8; ++i)
#pragma unroll
    for (int j = 0; j < 4; ++j) acc[i][j] = zero;

  gemm256(Ab, Bb, lds, acc);

  const int t = threadIdx.x, lane = t & 63, wave = t >> 6;
  const int wr = wave >> 2, wc = wave & 3;
  const int er = (lane >> 4) * 4, ec = lane & 15;
  const int tgt = bx >> 2;                        // 0:Q 1:K 2:V (uniform)
  const float* bias = (tgt == 0) ? bq : (tgt == 1) ? bk : bvp;

#pragma unroll
  for (int n4 = 0; n4 < 4; ++n4) {
    const int col = (bx & 3) * 256 + wc * 64 + n4 * 16 + ec;   // 0..1023
    const float bval = bias[col];
#pragma unroll
    for (int m8 = 0; m8 < 8; ++m8) {
      const long grow0 = (long)by * 256 + wr * 128 + m8 * 16 + er;
      if (tgt < 2) {
        __half* o = (tgt == 0) ? Qh : Kh;
#pragma unroll
        for (int r = 0; r < 4; ++r)
          o[(grow0 + r) * 1024 + col] = __float2half(acc[m8][n4][r] + bval);
      } else {
        const long b  = grow0 >> 11;              // batch
        const long ml = grow0 & 2047;             // aligned to 4
        f16x4 v4;
#pragma unroll
        for (int r = 0; r < 4; ++r) v4[r] = (_Float16)(acc[m8][n4][r] + bval);
        *(f16x4*)&Vt[b * 2097152 + (long)col * 2048 + ml] = v4;
      }
    }
  }
}

// ---------------------------------------------------------------------------
// QK^T on the 8-phase core with fused partial softmax, 64-col chunks.
// Wave (wr,wc) owns 128 rows x 64 cols -> chunk cc = bx*4+wc, exactly as the
// stats layout PM/PS[z][32][2048] expects. grid (8, 8, B).
// ---------------------------------------------------------------------------
__global__ __launch_bounds__(512, 2)
void qk256_kernel(const ushort_t* __restrict__ Q, const ushort_t* __restrict__ Kh,
                  __half* __restrict__ S, float* __restrict__ PM, float* __restrict__ PS)
{
  __shared__ __align__(16) ushort_t lds[65536];

  const int nb = gridDim.x * gridDim.y;
  int id = blockIdx.y * gridDim.x + blockIdx.x;
  id = (id & 7) * (nb >> 3) + (id >> 3);
  const int bx = id % gridDim.x;                  // K-tile
  const int by = id / gridDim.x;                  // Q-tile
  const long z = blockIdx.z;

  const ushort_t* Ab = Q  + z * 2048 * 1024 + (long)by * 256 * 1024;
  const ushort_t* Bb = Kh + z * 2048 * 1024 + (long)bx * 256 * 1024;
  __half* Sb = S + z * 2048 * 2048;

  f32x4 acc[8][4];
  const f32x4 zero = {0.0f, 0.0f, 0.0f, 0.0f};
#pragma unroll
  for (int i = 0; i < 8; ++i)
#pragma unroll
    for (int j = 0; j < 4; ++j) acc[i][j] = zero;

  gemm256(Ab, Bb, lds, acc);

  const int t = threadIdx.x, lane = t & 63, wave = t >> 6;
  const int wr = wave >> 2, wc = wave & 3;
  const int er = (lane >> 4) * 4, ec = lane & 15;
  const int cc = bx * 4 + wc;                     // 0..31
  float* PMb = PM + z * 32 * 2048 + (long)cc * 2048;
  float* PSb = PS + z * 32 * 2048 + (long)cc * 2048;

#pragma unroll
  for (int m8 = 0; m8 < 8; ++m8)
#pragma unroll
    for (int r = 0; r < 4; ++r) {
      float m = fmaxf(fmaxf(acc[m8][0][r], acc[m8][1][r]),
                      fmaxf(acc[m8][2][r], acc[m8][3][r]));
      m = fmaxf(m, __shfl_xor(m, 1));   // reduce over the 16 ec lanes
      m = fmaxf(m, __shfl_xor(m, 2));
      m = fmaxf(m, __shfl_xor(m, 4));
      m = fmaxf(m, __shfl_xor(m, 8));
      float s = 0.0f;
#pragma unroll
      for (int n4 = 0; n4 < 4; ++n4) {
        const float e = __expf(acc[m8][n4][r] - m);
        acc[m8][n4][r] = e;
        s += e;
      }
      s += __shfl_xor(s, 1);
      s += __shfl_xor(s, 2);
      s += __shfl_xor(s, 4);
      s += __shfl_xor(s, 8);
      if (ec == 0) {
        const long row = (long)by * 256 + wr * 128 + m8 * 16 + er + r;
        PMb[row] = m;
        PSb[row] = s;
      }
    }

  // store p_unnorm = exp(s - m_chunk) fp16
#pragma unroll
  for (int n4 = 0; n4 < 4; ++n4) {
    const long col = (long)bx * 256 + wc * 64 + n4 * 16 + ec;
#pragma unroll
    for (int m8 = 0; m8 < 8; ++m8)
#pragma unroll
      for (int r = 0; r < 4; ++r) {
        const long grow = (long)by * 256 + wr * 128 + m8 * 16 + er + r;
        Sb[grow * 2048 + col] = __float2half(acc[m8][n4][r]);
      }
  }
}

// ---------------------------------------------------------------------------
// Fold 32 chunk partials into per-(row,chunk) scale = exp(pm-m)/l.
// ---------------------------------------------------------------------------
__global__ __launch_bounds__(256)
void softmax_reduce_kernel(const float* __restrict__ PM, const float* __restrict__ PS,
                           float* __restrict__ Sc)
{
  const int r = blockIdx.x * 256 + threadIdx.x;   // 0..8191
  const int b = r >> 11, row = r & 2047;
  const long base = (long)b * 32 * 2048 + row;
  float m = -3.4e38f;
#pragma unroll
  for (int cb = 0; cb < 32; ++cb) m = fmaxf(m, PM[base + cb * 2048]);
  float l = 0.0f;
#pragma unroll
  for (int cb = 0; cb < 32; ++cb) l += PS[base + cb * 2048] * __expf(PM[base + cb * 2048] - m);
  const float inv = 1.0f / l;
#pragma unroll
  for (int cb = 0; cb < 32; ++cb) Sc[base + cb * 2048] = __expf(PM[base + cb * 2048] - m) * inv;
}

// ---------------------------------------------------------------------------
// PV: Out[m][e] = sum_k (S[m][k]*scale[m][k>>6]) * Vt[e][k]. (old structure)
// ---------------------------------------------------------------------------
__global__ __launch_bounds__(256)
void pv_gemm_kernel(const ushort_t* __restrict__ S, const ushort_t* __restrict__ Vt,
                    const float* __restrict__ Sc, float* __restrict__ Out)
{
  const int K = 2048;
  __shared__ ushort_t As[2][128 * 32];
  __shared__ ushort_t Bs[2][128 * 32];

  const int t    = threadIdx.x;
  const int lane = t & 63;
  const int wave = t >> 6;
  const int wm   = (wave >> 1) * 64;
  const int wn   = (wave & 1) * 64;
  const long z   = blockIdx.z;

  const ushort_t* Ab = S + z * 2048 * 2048 + (long)blockIdx.y * 128 * K;
  const ushort_t* Bb = Vt + z * 1024 * 2048 + (long)blockIdx.x * 128 * K;
  const float* Scb = Sc + z * 32 * 2048;
  float* Cb = Out + z * 2048 * 1024;

  const int ldr = t >> 2;
  const int swzs = (ldr & 3) ^ ((ldr >> 2) & 3);
  const int ldc = ((t & 3) ^ swzs) * 8;
  const int frow = lane & 15;
  const int fsz  = (frow & 3) ^ ((frow >> 2) & 3);
  const int fo   = (((lane >> 4) ^ fsz)) * 8;

  const int arow0 = blockIdx.y * 128 + wm + frow;

  f32x4 acc[4][4];
  const f32x4 zero = {0.0f, 0.0f, 0.0f, 0.0f};
#pragma unroll
  for (int i = 0; i < 4; ++i)
#pragma unroll
    for (int j = 0; j < 4; ++j) acc[i][j] = zero;

  for (int k0 = 0; k0 < K; k0 += 64) {
    const int cb = k0 >> 6;
    _Float16 sc16[4];
#pragma unroll
    for (int i = 0; i < 4; ++i)
      sc16[i] = (_Float16)Scb[(long)cb * 2048 + arow0 + i * 16];

    __syncthreads();
    const ushort_t* ga = Ab + (long)ldr * K + k0 + ldc;
    const ushort_t* gb = Bb + (long)ldr * K + k0 + ldc;
#pragma unroll
    for (int h = 0; h < 2; ++h) {
      async_load16(ga + h * 32,                &As[h][t * 8]);
      async_load16(ga + h * 32 + 64 * (long)K, &As[h][2048 + t * 8]);
      async_load16(gb + h * 32,                &Bs[h][t * 8]);
      async_load16(gb + h * 32 + 64 * (long)K, &Bs[h][2048 + t * 8]);
    }
    __syncthreads();
#pragma unroll
    for (int h = 0; h < 2; ++h) {
      f16x8 af[4], bf[4];
#pragma unroll
      for (int i = 0; i < 4; ++i) {
        af[i] = *(const f16x8*)&As[h][(wm + i * 16 + frow) * 32 + fo] * sc16[i];
        bf[i] = *(const f16x8*)&Bs[h][(wn + i * 16 + frow) * 32 + fo];
      }
#pragma unroll
      for (int mi = 0; mi < 4; ++mi)
#pragma unroll
        for (int ni = 0; ni < 4; ++ni)
          acc[mi][ni] = __builtin_amdgcn_mfma_f32_16x16x32_f16(af[mi], bf[ni], acc[mi][ni], 0, 0, 0);
    }
  }

  const int er = (lane >> 4) * 4;
  const int ec = lane & 15;
#pragma unroll
  for (int ni = 0; ni < 4; ++ni) {
    const int gcol = blockIdx.x * 128 + wn + ni * 16 + ec;
#pragma unroll
    for (int mi = 0; mi < 4; ++mi) {
#pragma unroll
      for (int r = 0; r < 4; ++r) {
        const long grow = (long)blockIdx.y * 128 + wm + mi * 16 + er + r;
        Cb[grow * 1024 + gcol] = acc[mi][ni][r];
      }
    }
  }
}

// ---------------------------------------------------------------------------
// fp32 -> fp16 elementwise, 8 elems/thread, 16B stores.
// ---------------------------------------------------------------------------
__global__ __launch_bounds__(256)
void cvt_f32_f16_kernel(const float* __restrict__ src, __half* __restrict__ dst, long n)
{
  const long i = ((long)blockIdx.x * 256 + threadIdx.x) * 8;
  if (i + 8 > n) return;
  const float4 a = *(const float4*)(src + i);
  const float4 b = *(const float4*)(src + i + 4);
  f16x8 h;
  h[0] = (_Float16)a.x; h[1] = (_Float16)a.y; h[2] = (_Float16)a.z; h[3] = (_Float16)a.w;
  h[4] = (_Float16)b.x; h[5] = (_Float16)b.y; h[6] = (_Float16)b.z; h[7] = (_Float16)b.w;
  *(f16x8*)((ushort_t*)dst + i) = h;
}

// ---------------------------------------------------------------------------
// Batched weight transpose+convert: dst[z][c][r] = (fp16)srcz[r][c], 1024x1024.
// ---------------------------------------------------------------------------
__global__ __launch_bounds__(256)
void transpose_cvt3_kernel(const float* __restrict__ W0, const float* __restrict__ W1,
                           const float* __restrict__ W2, __half* __restrict__ dst)
{
  __shared__ float tile[32][33];
  const int z = blockIdx.z;
  const float* src = (z == 0) ? W0 : (z == 1) ? W1 : W2;
  __half* d = dst + (long)z * 1024 * 1024;
  const int c0 = blockIdx.x * 32;
  const int r0 = blockIdx.y * 32;
  const int tx = threadIdx.x & 31;
  const int ty = threadIdx.x >> 5;
#pragma unroll
  for (int i = 0; i < 32; i += 8)
    tile[ty + i][tx] = src[(long)(r0 + ty + i) * 1024 + (c0 + tx)];
  __syncthreads();
#pragma unroll
  for (int i = 0; i < 32; i += 8)
    d[(long)(c0 + ty + i) * 1024 + (r0 + tx)] = __float2half(tile[tx][ty + i]);
}

// ---------------------------------------------------------------------------
extern "C" void kernel_launch(void* const* d_in, const int* in_sizes, int n_in,
                              void* d_out, int out_size, void* d_ws, size_t ws_size,
                              hipStream_t stream)
{
  const int  Bb = 4, Nn = 2048, Dd = 1024;
  const long BN = (long)Bb * Nn;  // 8192

  const float* X  = (const float*)d_in[0];
  const float* Wq = (const float*)d_in[1];
  const float* bq = (const float*)d_in[2];
  const float* Wk = (const float*)d_in[3];
  const float* bk = (const float*)d_in[4];
  const float* Wv = (const float*)d_in[5];
  const float* bv = (const float*)d_in[6];
  float* Out      = (float*)d_out;

  uint8_t* w = (uint8_t*)d_ws;
  ushort_t* Wt = (ushort_t*)w;  w += (size_t)3 * Dd * Dd * 2;  // Wq^T|Wk^T|Wv^T fp16

  transpose_cvt3_kernel<<<dim3(Dd / 32, Dd / 32, 3), 256, 0, stream>>>(Wq, Wk, Wv, (__half*)Wt);

  const size_t statsBytes = (size_t)Bb * 32 * Nn * 4;   // 1 MB each
  const size_t fullNeed = (size_t)3 * Dd * Dd * 2       // Wt
                        + 4 * ((size_t)BN * Dd * 2)     // Xh, Q, K, Vt fp16
                        + (size_t)Bb * Nn * Nn * 2      // S fp16
                        + 3 * statsBytes;               // PM, PS, Sc

  if (ws_size >= fullNeed) {
    ushort_t* Xh = (ushort_t*)w;  w += (size_t)BN * Dd * 2;
    ushort_t* Q  = (ushort_t*)w;  w += (size_t)BN * Dd * 2;
    ushort_t* Kb = (ushort_t*)w;  w += (size_t)BN * Dd * 2;
    ushort_t* Vt = (ushort_t*)w;  w += (size_t)BN * Dd * 2;  // [B][Dd][Nn]
    ushort_t* S  = (ushort_t*)w;  w += (size_t)Bb * Nn * Nn * 2;
    float*    PM = (float*)w;     w += statsBytes;
    float*    PS = (float*)w;     w += statsBytes;
    float*    Sc = (float*)w;

    cvt_f32_f16_kernel<<<dim3((unsigned)(BN * Dd / (8 * 256))), 256, 0, stream>>>(
        X, (__half*)Xh, BN * Dd);

    qkv256_kernel<<<dim3(3 * Dd / 256, BN / 256, 1), 512, 0, stream>>>(
        Xh, Wt, bq, bk, bv, (__half*)Q, (__half*)Kb, Vt);

    qk256_kernel<<<dim3(Nn / 256, Nn / 256, Bb), 512, 0, stream>>>(
        Q, Kb, (__half*)S, PM, PS);

    softmax_reduce_kernel<<<dim3((unsigned)(Bb * Nn / 256)), 256, 0, stream>>>(PM, PS, Sc);

    pv_gemm_kernel<<<dim3(Dd / 128, Nn / 128, Bb), 256, 0, stream>>>(
        S, Vt, Sc, Out);
  } else {
    // Per-batch fallback (~32 MB ws): same kernels, z-extent 1
    ushort_t* Xh = (ushort_t*)w;  w += (size_t)Nn * Dd * 2;
    ushort_t* Q  = (ushort_t*)w;  w += (size_t)Nn * Dd * 2;
    ushort_t* Kb = (ushort_t*)w;  w += (size_t)Nn * Dd * 2;
    ushort_t* Vt = (ushort_t*)w;  w += (size_t)Nn * Dd * 2;
    ushort_t* S  = (ushort_t*)w;  w += (size_t)Nn * Nn * 2;
    float*    PM = (float*)w;     w += (size_t)32 * Nn * 4;
    float*    PS = (float*)w;     w += (size_t)32 * Nn * 4;
    float*    Sc = (float*)w;

    for (int b = 0; b < Bb; ++b) {
      const float* Xb = X + (long)b * Nn * Dd;
      cvt_f32_f16_kernel<<<dim3((unsigned)((long)Nn * Dd / (8 * 256))), 256, 0, stream>>>(
          Xb, (__half*)Xh, (long)Nn * Dd);
      qkv256_kernel<<<dim3(3 * Dd / 256, Nn / 256, 1), 512, 0, stream>>>(
          Xh, Wt, bq, bk, bv, (__half*)Q, (__half*)Kb, Vt);
      qk256_kernel<<<dim3(Nn / 256, Nn / 256, 1), 512, 0, stream>>>(
          Q, Kb, (__half*)S, PM, PS);
      softmax_reduce_kernel<<<dim3((unsigned)(Nn / 256)), 256, 0, stream>>>(PM, PS, Sc);
      pv_gemm_kernel<<<dim3(Dd / 128, Nn / 128, 1), 256, 0, stream>>>(
          S, Vt, Sc, Out + (long)b * Nn * Dd);
    }
  }
}

// Round 3
// 267.294 us; speedup vs baseline: 1.0295x; 1.0295x over previous
//
#include <hip/hip_runtime.h>
#include <hip/hip_bf16.h>
#include <hip/hip_fp16.h>
#include <stdint.h>
#include <math.h>

// ---------------------------------------------------------------------------
// AttentionLayer: Q=XWq+bq, K=XWk+bk, V=XWv+bv; O = softmax(QK^T) V
// B=4, N=2048, D=1024. fp32 I/O; internals fp16, accumulation fp32.
// R9: R8 showed the 8-phase core runs ~860 TF but qkv's 384-block grid on
// 256 CUs (1 block/CU) wastes 25% in the 2nd dispatch round. This round:
//  - NEW 256Mx128N 8-phase core (same choreography, A-half=2 insts,
//    B-half=1 inst, gates vmcnt(5)); LDS 96KB
//  - qkv -> 24x32 = 768 blocks = 3 full rounds (no tail)
//  - pv  -> same core w/ chunk-scale folded into A-frag reads (scale
//    prefetched 1 iter ahead; loads always older than the kept-5 at gates);
//    grid 8x8x4 = 256 = 1 round
//  - qk256 kept byte-identical (control: 16-MFMA phases, perfect packing)
// ---------------------------------------------------------------------------

typedef unsigned short ushort_t;
typedef __attribute__((ext_vector_type(8))) _Float16  f16x8;
typedef __attribute__((ext_vector_type(4))) _Float16  f16x4;
typedef __attribute__((ext_vector_type(4))) float     f32x4;

__device__ __forceinline__ void async_load16(const void* g, void* l) {
  __builtin_amdgcn_global_load_lds(
      (const __attribute__((address_space(1))) void*)g,
      (__attribute__((address_space(3))) void*)l, 16, 0, 0);
}

#define BARR do { __builtin_amdgcn_sched_barrier(0); \
                  __builtin_amdgcn_s_barrier();      \
                  __builtin_amdgcn_sched_barrier(0); } while (0)

// ===========================================================================
// 256x256 8-phase core (qk256 only; unchanged from R8, proven)
// ===========================================================================
#define A0OFF 0
#define B0OFF 16384
#define A1OFF 32768
#define B1OFF 49152

template<int SHIFT>
__device__ __forceinline__ void stage_half(const ushort_t* __restrict__ gb,
                                           int k0, int q, ushort_t* lt, int t)
{
#pragma unroll
  for (int j = 0; j < 2; ++j) {
    const int i   = j * 64 + (t >> 3);
    const int row = ((i >> SHIFT) << (SHIFT + 1)) | (q << SHIFT) | (i & ((1 << SHIFT) - 1));
    const int ch  = (t & 7) ^ (row & 7);
    async_load16(gb + (long)row * 1024 + k0 + ch * 8, lt + row * 64 + (t & 7) * 8);
  }
}

#define RD_A(TP, QM)                                                          \
  do { _Pragma("unroll") for (int m_ = 0; m_ < 4; ++m_) {                     \
    af[m_][0] = *(const f16x8*)&(TP)[(arow0 + (QM)*64 + m_*16) * 64 + ck0];   \
    af[m_][1] = *(const f16x8*)&(TP)[(arow0 + (QM)*64 + m_*16) * 64 + ck1];   \
  } } while (0)

#define RD_B(TP, QN)                                                          \
  do { _Pragma("unroll") for (int n_ = 0; n_ < 2; ++n_) {                     \
    bf[n_][0] = *(const f16x8*)&(TP)[(brow0 + (QN)*32 + n_*16) * 64 + ck0];   \
    bf[n_][1] = *(const f16x8*)&(TP)[(brow0 + (QN)*32 + n_*16) * 64 + ck1];   \
  } } while (0)

#define MM(QM, QN)                                                            \
  do { __builtin_amdgcn_s_setprio(1);                                         \
  _Pragma("unroll") for (int kh_ = 0; kh_ < 2; ++kh_)                         \
    _Pragma("unroll") for (int m_ = 0; m_ < 4; ++m_)                          \
      _Pragma("unroll") for (int n_ = 0; n_ < 2; ++n_)                        \
        acc[(QM)*4+m_][(QN)*2+n_] = __builtin_amdgcn_mfma_f32_16x16x32_f16(   \
            af[m_][kh_], bf[n_][kh_], acc[(QM)*4+m_][(QN)*2+n_], 0, 0, 0);    \
  __builtin_amdgcn_s_setprio(0); } while (0)

template<bool LAST>
__device__ __forceinline__ void iter256(const ushort_t* __restrict__ Ab,
                                        const ushort_t* __restrict__ Bb,
                                        ushort_t* lds, f32x4 (&acc)[8][4],
                                        int ka, int t, int arow0, int brow0,
                                        int ck0, int ck1)
{
  const int kb = ka + 64, kc = ka + 128, kd = ka + 192;
  f16x8 af[4][2], bf[2][2];

  RD_A(lds + A0OFF, 0); RD_B(lds + B0OFF, 0);
  stage_half<5>(Bb, kb, 0, lds + B1OFF, t);
  BARR; MM(0, 0); BARR;

  RD_B(lds + B0OFF, 1);
  if constexpr (!LAST) stage_half<6>(Ab, kc, 0, lds + A0OFF, t);
  BARR; MM(0, 1); BARR;

  RD_A(lds + A0OFF, 1);
  if constexpr (!LAST) stage_half<5>(Bb, kc, 1, lds + B0OFF, t);
  BARR; MM(1, 1); BARR;

  RD_B(lds + B0OFF, 0);
  if constexpr (!LAST) stage_half<6>(Ab, kc, 1, lds + A0OFF, t);
  BARR; MM(1, 0);
  if constexpr (LAST) asm volatile("s_waitcnt vmcnt(0)" ::: "memory");
  else                asm volatile("s_waitcnt vmcnt(6)" ::: "memory");
  BARR;

  RD_A(lds + A1OFF, 0); RD_B(lds + B1OFF, 0);
  if constexpr (!LAST) stage_half<5>(Bb, kc, 0, lds + B0OFF, t);
  BARR; MM(0, 0); BARR;

  RD_B(lds + B1OFF, 1);
  if constexpr (!LAST) stage_half<6>(Ab, kd, 0, lds + A1OFF, t);
  BARR; MM(0, 1); BARR;

  RD_A(lds + A1OFF, 1);
  if constexpr (!LAST) stage_half<5>(Bb, kd, 1, lds + B1OFF, t);
  BARR; MM(1, 1); BARR;

  RD_B(lds + B1OFF, 0);
  if constexpr (!LAST) stage_half<6>(Ab, kd, 1, lds + A1OFF, t);
  BARR; MM(1, 0);
  if constexpr (!LAST) asm volatile("s_waitcnt vmcnt(6)" ::: "memory");
  BARR;
}

__device__ __forceinline__ void gemm256(const ushort_t* __restrict__ Ab,
                                        const ushort_t* __restrict__ Bb,
                                        ushort_t* lds, f32x4 (&acc)[8][4])
{
  const int t    = threadIdx.x;
  const int lane = t & 63;
  const int wave = t >> 6;
  const int wr   = wave >> 2;
  const int wc   = wave & 3;
  const int arow0 = wr * 128 + (lane & 15);
  const int brow0 = wc * 64  + (lane & 15);
  const int ck0 = (((lane >> 4)    ) ^ (lane & 7)) * 8;
  const int ck1 = ((4 + (lane >> 4)) ^ (lane & 7)) * 8;

  stage_half<6>(Ab,  0, 0, lds + A0OFF, t);
  stage_half<5>(Bb,  0, 1, lds + B0OFF, t);
  stage_half<6>(Ab,  0, 1, lds + A0OFF, t);
  stage_half<5>(Bb,  0, 0, lds + B0OFF, t);
  stage_half<6>(Ab, 64, 0, lds + A1OFF, t);
  stage_half<5>(Bb, 64, 1, lds + B1OFF, t);
  stage_half<6>(Ab, 64, 1, lds + A1OFF, t);
  asm volatile("s_waitcnt vmcnt(6)" ::: "memory");
  BARR;

#pragma unroll 1
  for (int it = 0; it < 7; ++it)
    iter256<false>(Ab, Bb, lds, acc, it * 128, t, arow0, brow0, ck0, ck1);
  iter256<true>(Ab, Bb, lds, acc, 896, t, arow0, brow0, ck0, ck1);
}

// ===========================================================================
// NEW 256Mx128N 8-phase core. LDS (ushort): A0 256x64 @0, B0 128x64 @16384,
// A1 @24576, B1 @40960; total 49152 ushorts = 96 KB. 8 waves as 4M x 2N,
// wave output 64x64, acc[4][4]. Halves split on row-bit5 (A: 2 insts/thread,
// B: 1 inst/thread). Gates vmcnt(5) = keep {newest A-half(2)+B-half(1)+
// A-half(2)}. Same phase/stage choreography as the proven 256^2 core.
// ===========================================================================
#define NA0 0
#define NB0 16384
#define NA1 24576
#define NB1 40960

__device__ __forceinline__ void stage_A_n(const ushort_t* __restrict__ gb, long ldk,
                                          int k0, int q, ushort_t* lt, int t)
{
#pragma unroll
  for (int j = 0; j < 2; ++j) {
    const int i   = j * 64 + (t >> 3);                    // 0..127
    const int row = ((i >> 5) << 6) | (q << 5) | (i & 31); // 0..255, bit5==q
    const int ch  = (t & 7) ^ (row & 7);
    async_load16(gb + (long)row * ldk + k0 + ch * 8, lt + row * 64 + (t & 7) * 8);
  }
}

__device__ __forceinline__ void stage_B_n(const ushort_t* __restrict__ gb, long ldk,
                                          int k0, int q, ushort_t* lt, int t)
{
  const int i   = t >> 3;                                 // 0..63
  const int row = ((i >> 5) << 6) | (q << 5) | (i & 31);  // 0..127, bit5==q
  const int ch  = (t & 7) ^ (row & 7);
  async_load16(gb + (long)row * ldk + k0 + ch * 8, lt + row * 64 + (t & 7) * 8);
}

#define RDN_A(TP, QM)                                                         \
  do { _Pragma("unroll") for (int m_ = 0; m_ < 2; ++m_) {                     \
    af[m_][0] = *(const f16x8*)&(TP)[(arow_l + (QM)*32 + m_*16) * 64 + ck0];  \
    af[m_][1] = *(const f16x8*)&(TP)[(arow_l + (QM)*32 + m_*16) * 64 + ck1];  \
  } } while (0)

#define RDN_AS(TP, QM, S)                                                     \
  do { _Pragma("unroll") for (int m_ = 0; m_ < 2; ++m_) {                     \
    af[m_][0] = *(const f16x8*)&(TP)[(arow_l + (QM)*32 + m_*16) * 64 + ck0] * (S)[(QM)*2+m_]; \
    af[m_][1] = *(const f16x8*)&(TP)[(arow_l + (QM)*32 + m_*16) * 64 + ck1] * (S)[(QM)*2+m_]; \
  } } while (0)

#define RDN_B(TP, QN)                                                         \
  do { _Pragma("unroll") for (int n_ = 0; n_ < 2; ++n_) {                     \
    bf[n_][0] = *(const f16x8*)&(TP)[(brow_l + (QN)*32 + n_*16) * 64 + ck0];  \
    bf[n_][1] = *(const f16x8*)&(TP)[(brow_l + (QN)*32 + n_*16) * 64 + ck1];  \
  } } while (0)

#define MMN(QM, QN)                                                           \
  do { __builtin_amdgcn_s_setprio(1);                                         \
  _Pragma("unroll") for (int kh_ = 0; kh_ < 2; ++kh_)                         \
    _Pragma("unroll") for (int m_ = 0; m_ < 2; ++m_)                          \
      _Pragma("unroll") for (int n_ = 0; n_ < 2; ++n_)                        \
        acc[(QM)*2+m_][(QN)*2+n_] = __builtin_amdgcn_mfma_f32_16x16x32_f16(   \
            af[m_][kh_], bf[n_][kh_], acc[(QM)*2+m_][(QN)*2+n_], 0, 0, 0);    \
  __builtin_amdgcn_s_setprio(0); } while (0)

// Stage slots (same positions as proven core): ph1 b.B0 | ph2 c.A0 | ph3 c.B1
// | ph4 c.A1 GATE | ph5 c.B0 | ph6 d.A0 | ph7 d.B1 | ph8 d.A1 GATE.
// Gate ph4: retire through b.B0 -> keep c.{A1,B1,A0} = 5 insts -> vmcnt(5).
// Gate ph8: retire through c.B0 -> keep d.{A1,B1,A0} = 5 insts -> vmcnt(5).
template<bool LAST>
__device__ __forceinline__ void iter_n(const ushort_t* __restrict__ Ab,
                                       const ushort_t* __restrict__ Bb,
                                       long lda, long ldb,
                                       ushort_t* lds, f32x4 (&acc)[4][4],
                                       int ka, int t, int arow_l, int brow_l,
                                       int ck0, int ck1)
{
  const int kb = ka + 64, kc = ka + 128, kd = ka + 192;
  f16x8 af[2][2], bf[2][2];

  RDN_A(lds + NA0, 0); RDN_B(lds + NB0, 0);
  stage_B_n(Bb, ldb, kb, 0, lds + NB1, t);
  BARR; MMN(0, 0); BARR;

  RDN_B(lds + NB0, 1);
  if constexpr (!LAST) stage_A_n(Ab, lda, kc, 0, lds + NA0, t);
  BARR; MMN(0, 1); BARR;

  RDN_A(lds + NA0, 1);
  if constexpr (!LAST) stage_B_n(Bb, ldb, kc, 1, lds + NB0, t);
  BARR; MMN(1, 1); BARR;

  RDN_B(lds + NB0, 0);
  if constexpr (!LAST) stage_A_n(Ab, lda, kc, 1, lds + NA0, t);
  BARR; MMN(1, 0);
  if constexpr (LAST) asm volatile("s_waitcnt vmcnt(0)" ::: "memory");
  else                asm volatile("s_waitcnt vmcnt(5)" ::: "memory");
  BARR;

  RDN_A(lds + NA1, 0); RDN_B(lds + NB1, 0);
  if constexpr (!LAST) stage_B_n(Bb, ldb, kc, 0, lds + NB0, t);
  BARR; MMN(0, 0); BARR;

  RDN_B(lds + NB1, 1);
  if constexpr (!LAST) stage_A_n(Ab, lda, kd, 0, lds + NA1, t);
  BARR; MMN(0, 1); BARR;

  RDN_A(lds + NA1, 1);
  if constexpr (!LAST) stage_B_n(Bb, ldb, kd, 1, lds + NB1, t);
  BARR; MMN(1, 1); BARR;

  RDN_B(lds + NB1, 0);
  if constexpr (!LAST) stage_A_n(Ab, lda, kd, 1, lds + NA1, t);
  BARR; MMN(1, 0);
  if constexpr (!LAST) asm volatile("s_waitcnt vmcnt(5)" ::: "memory");
  BARR;
}

// PV variant: chunk-scale S (per 64-k-chunk, per row) folded into A-frag
// reads; next iter's scales prefetched at iter top (always older than the
// kept-5 at both gates -> retired automatically, no gate interference).
template<bool LAST>
__device__ __forceinline__ void pv_iter_n(const ushort_t* __restrict__ Ab,
                                          const ushort_t* __restrict__ Bb,
                                          ushort_t* lds, f32x4 (&acc)[4][4],
                                          int ka, int t, int arow_l, int brow_l,
                                          int ck0, int ck1,
                                          float (&scc)[2][4],
                                          const float* __restrict__ Scb, int arow_abs)
{
  const int kb = ka + 64, kc = ka + 128, kd = ka + 192;
  f16x8 af[2][2], bf[2][2];

  float scn[2][4];
  if constexpr (!LAST) {
    const int cbn = (ka >> 6) + 2;
#pragma unroll
    for (int h = 0; h < 2; ++h)
#pragma unroll
      for (int s = 0; s < 4; ++s)
        scn[h][s] = Scb[(long)(cbn + h) * 2048 + arow_abs + s * 16];
  }
  _Float16 sa[4], sb[4];
#pragma unroll
  for (int s = 0; s < 4; ++s) { sa[s] = (_Float16)scc[0][s]; sb[s] = (_Float16)scc[1][s]; }

  RDN_AS(lds + NA0, 0, sa); RDN_B(lds + NB0, 0);
  stage_B_n(Bb, 2048, kb, 0, lds + NB1, t);
  BARR; MMN(0, 0); BARR;

  RDN_B(lds + NB0, 1);
  if constexpr (!LAST) stage_A_n(Ab, 2048, kc, 0, lds + NA0, t);
  BARR; MMN(0, 1); BARR;

  RDN_AS(lds + NA0, 1, sa);
  if constexpr (!LAST) stage_B_n(Bb, 2048, kc, 1, lds + NB0, t);
  BARR; MMN(1, 1); BARR;

  RDN_B(lds + NB0, 0);
  if constexpr (!LAST) stage_A_n(Ab, 2048, kc, 1, lds + NA0, t);
  BARR; MMN(1, 0);
  if constexpr (LAST) asm volatile("s_waitcnt vmcnt(0)" ::: "memory");
  else                asm volatile("s_waitcnt vmcnt(5)" ::: "memory");
  BARR;

  RDN_AS(lds + NA1, 0, sb); RDN_B(lds + NB1, 0);
  if constexpr (!LAST) stage_B_n(Bb, 2048, kc, 0, lds + NB0, t);
  BARR; MMN(0, 0); BARR;

  RDN_B(lds + NB1, 1);
  if constexpr (!LAST) stage_A_n(Ab, 2048, kd, 0, lds + NA1, t);
  BARR; MMN(0, 1); BARR;

  RDN_AS(lds + NA1, 1, sb);
  if constexpr (!LAST) stage_B_n(Bb, 2048, kd, 1, lds + NB1, t);
  BARR; MMN(1, 1); BARR;

  RDN_B(lds + NB1, 0);
  if constexpr (!LAST) stage_A_n(Ab, 2048, kd, 1, lds + NA1, t);
  BARR; MMN(1, 0);
  if constexpr (!LAST) asm volatile("s_waitcnt vmcnt(5)" ::: "memory");
  BARR;

  if constexpr (!LAST) {
#pragma unroll
    for (int h = 0; h < 2; ++h)
#pragma unroll
      for (int s = 0; s < 4; ++s) scc[h][s] = scn[h][s];
  }
}

// Prologue (shared pattern): a.A0,a.B0,a.A1,a.B1,b.A0,b.B1,b.A1 (11 insts);
// keep newest 5 = b.{A0,B1,A1} -> vmcnt(5); a fully landed.
#define PROLOGUE_N(LDA, LDB)                                \
  do {                                                      \
    stage_A_n(Ab, (LDA),  0, 0, lds + NA0, t);              \
    stage_B_n(Bb, (LDB),  0, 0, lds + NB0, t);              \
    stage_A_n(Ab, (LDA),  0, 1, lds + NA0, t);              \
    stage_B_n(Bb, (LDB),  0, 1, lds + NB0, t);              \
    stage_A_n(Ab, (LDA), 64, 0, lds + NA1, t);              \
    stage_B_n(Bb, (LDB), 64, 1, lds + NB1, t);              \
    stage_A_n(Ab, (LDA), 64, 1, lds + NA1, t);              \
    asm volatile("s_waitcnt vmcnt(5)" ::: "memory");        \
    BARR;                                                   \
  } while (0)

// ---------------------------------------------------------------------------
// Fused QKV projection on the 256x128 core. A = Xh [8192][1024],
// BT = Wt [3072][1024]. grid (24, 32) = 768 blocks = 3 full rounds.
// ---------------------------------------------------------------------------
__global__ __launch_bounds__(512, 2)
void qkv128n_kernel(const ushort_t* __restrict__ A, const ushort_t* __restrict__ BT,
                    const float* __restrict__ bq, const float* __restrict__ bk,
                    const float* __restrict__ bvp,
                    __half* __restrict__ Qh, __half* __restrict__ Kh,
                    ushort_t* __restrict__ Vt)
{
  __shared__ __align__(16) ushort_t lds[49152];   // 96 KB

  const int nb = gridDim.x * gridDim.y;           // 768, %8==0
  int id = blockIdx.y * gridDim.x + blockIdx.x;
  id = (id & 7) * (nb >> 3) + (id >> 3);          // bijective XCD swizzle
  const int bx = id % gridDim.x;                  // 0..23 (N-tile of 128)
  const int by = id / gridDim.x;                  // 0..31 (M-tile of 256)

  const ushort_t* Ab = A  + (long)by * 256 * 1024;
  const ushort_t* Bb = BT + (long)bx * 128 * 1024;

  const int t    = threadIdx.x;
  const int lane = t & 63;
  const int wave = t >> 6;
  const int wr   = wave >> 1;                     // 0..3 (M, 64 rows each)
  const int wc   = wave & 1;                      // 0..1 (N, 64 cols each)
  const int arow_l = wr * 64 + (lane & 15);
  const int brow_l = wc * 64 + (lane & 15);
  const int ck0 = (((lane >> 4)    ) ^ (lane & 7)) * 8;
  const int ck1 = ((4 + (lane >> 4)) ^ (lane & 7)) * 8;

  f32x4 acc[4][4];
  const f32x4 zero = {0.0f, 0.0f, 0.0f, 0.0f};
#pragma unroll
  for (int i = 0; i < 4; ++i)
#pragma unroll
    for (int j = 0; j < 4; ++j) acc[i][j] = zero;

  PROLOGUE_N(1024, 1024);
#pragma unroll 1
  for (int it = 0; it < 7; ++it)
    iter_n<false>(Ab, Bb, 1024, 1024, lds, acc, it * 128, t, arow_l, brow_l, ck0, ck1);
  iter_n<true>(Ab, Bb, 1024, 1024, lds, acc, 896, t, arow_l, brow_l, ck0, ck1);

  const int er = (lane >> 4) * 4, ec = lane & 15;
  const int tgt = bx >> 3;                        // 0:Q 1:K 2:V (uniform)
  const float* bias = (tgt == 0) ? bq : (tgt == 1) ? bk : bvp;

#pragma unroll
  for (int ni = 0; ni < 4; ++ni) {
    const int col = (bx & 7) * 128 + wc * 64 + ni * 16 + ec;   // 0..1023
    const float bval = bias[col];
#pragma unroll
    for (int mi = 0; mi < 4; ++mi) {
      const long grow0 = (long)by * 256 + wr * 64 + mi * 16 + er;
      if (tgt < 2) {
        __half* o = (tgt == 0) ? Qh : Kh;
#pragma unroll
        for (int r = 0; r < 4; ++r)
          o[(grow0 + r) * 1024 + col] = __float2half(acc[mi][ni][r] + bval);
      } else {
        const long b  = grow0 >> 11;              // batch (256 | 2048 -> no crossing)
        const long ml = grow0 & 2047;             // aligned to 4
        f16x4 v4;
#pragma unroll
        for (int r = 0; r < 4; ++r) v4[r] = (_Float16)(acc[mi][ni][r] + bval);
        *(f16x4*)&Vt[b * 2097152 + (long)col * 2048 + ml] = v4;
      }
    }
  }
}

// ---------------------------------------------------------------------------
// QK^T on the 256x256 8-phase core (unchanged from R8 - control kernel).
// grid (8, 8, B) = 256 blocks.
// ---------------------------------------------------------------------------
__global__ __launch_bounds__(512, 2)
void qk256_kernel(const ushort_t* __restrict__ Q, const ushort_t* __restrict__ Kh,
                  __half* __restrict__ S, float* __restrict__ PM, float* __restrict__ PS)
{
  __shared__ __align__(16) ushort_t lds[65536];

  const int nb = gridDim.x * gridDim.y;
  int id = blockIdx.y * gridDim.x + blockIdx.x;
  id = (id & 7) * (nb >> 3) + (id >> 3);
  const int bx = id % gridDim.x;
  const int by = id / gridDim.x;
  const long z = blockIdx.z;

  const ushort_t* Ab = Q  + z * 2048 * 1024 + (long)by * 256 * 1024;
  const ushort_t* Bb = Kh + z * 2048 * 1024 + (long)bx * 256 * 1024;
  __half* Sb = S + z * 2048 * 2048;

  f32x4 acc[8][4];
  const f32x4 zero = {0.0f, 0.0f, 0.0f, 0.0f};
#pragma unroll
  for (int i = 0; i < 8; ++i)
#pragma unroll
    for (int j = 0; j < 4; ++j) acc[i][j] = zero;

  gemm256(Ab, Bb, lds, acc);

  const int t = threadIdx.x, lane = t & 63, wave = t >> 6;
  const int wr = wave >> 2, wc = wave & 3;
  const int er = (lane >> 4) * 4, ec = lane & 15;
  const int cc = bx * 4 + wc;                     // 0..31
  float* PMb = PM + z * 32 * 2048 + (long)cc * 2048;
  float* PSb = PS + z * 32 * 2048 + (long)cc * 2048;

#pragma unroll
  for (int m8 = 0; m8 < 8; ++m8)
#pragma unroll
    for (int r = 0; r < 4; ++r) {
      float m = fmaxf(fmaxf(acc[m8][0][r], acc[m8][1][r]),
                      fmaxf(acc[m8][2][r], acc[m8][3][r]));
      m = fmaxf(m, __shfl_xor(m, 1));
      m = fmaxf(m, __shfl_xor(m, 2));
      m = fmaxf(m, __shfl_xor(m, 4));
      m = fmaxf(m, __shfl_xor(m, 8));
      float s = 0.0f;
#pragma unroll
      for (int n4 = 0; n4 < 4; ++n4) {
        const float e = __expf(acc[m8][n4][r] - m);
        acc[m8][n4][r] = e;
        s += e;
      }
      s += __shfl_xor(s, 1);
      s += __shfl_xor(s, 2);
      s += __shfl_xor(s, 4);
      s += __shfl_xor(s, 8);
      if (ec == 0) {
        const long row = (long)by * 256 + wr * 128 + m8 * 16 + er + r;
        PMb[row] = m;
        PSb[row] = s;
      }
    }

#pragma unroll
  for (int n4 = 0; n4 < 4; ++n4) {
    const long col = (long)bx * 256 + wc * 64 + n4 * 16 + ec;
#pragma unroll
    for (int m8 = 0; m8 < 8; ++m8)
#pragma unroll
      for (int r = 0; r < 4; ++r) {
        const long grow = (long)by * 256 + wr * 128 + m8 * 16 + er + r;
        Sb[grow * 2048 + col] = __float2half(acc[m8][n4][r]);
      }
  }
}

// ---------------------------------------------------------------------------
// Fold 32 chunk partials into per-(row,chunk) scale = exp(pm-m)/l.
// ---------------------------------------------------------------------------
__global__ __launch_bounds__(256)
void softmax_reduce_kernel(const float* __restrict__ PM, const float* __restrict__ PS,
                           float* __restrict__ Sc)
{
  const int r = blockIdx.x * 256 + threadIdx.x;   // 0..8191
  const int b = r >> 11, row = r & 2047;
  const long base = (long)b * 32 * 2048 + row;
  float m = -3.4e38f;
#pragma unroll
  for (int cb = 0; cb < 32; ++cb) m = fmaxf(m, PM[base + cb * 2048]);
  float l = 0.0f;
#pragma unroll
  for (int cb = 0; cb < 32; ++cb) l += PS[base + cb * 2048] * __expf(PM[base + cb * 2048] - m);
  const float inv = 1.0f / l;
#pragma unroll
  for (int cb = 0; cb < 32; ++cb) Sc[base + cb * 2048] = __expf(PM[base + cb * 2048] - m) * inv;
}

// ---------------------------------------------------------------------------
// PV on the 256x128 core: Out[m][e] = sum_k (S[m][k]*sc[m][k>>6]) * Vt[e][k].
// grid (8, 8, 4) = 256 blocks = 1 full round. K = 2048.
// ---------------------------------------------------------------------------
__global__ __launch_bounds__(512, 2)
void pv128n_kernel(const ushort_t* __restrict__ S, const ushort_t* __restrict__ Vt,
                   const float* __restrict__ Sc, float* __restrict__ Out)
{
  __shared__ __align__(16) ushort_t lds[49152];   // 96 KB

  const int nb = gridDim.x * gridDim.y;           // 64, %8==0
  int id = blockIdx.y * gridDim.x + blockIdx.x;
  id = (id & 7) * (nb >> 3) + (id >> 3);
  const int bx = id % gridDim.x;                  // 0..7 (N-tile: Out cols / Vt rows)
  const int by = id / gridDim.x;                  // 0..7 (M-tile: S rows)
  const long z = blockIdx.z;

  const ushort_t* Ab = S  + z * 4194304 + (long)by * 256 * 2048;
  const ushort_t* Bb = Vt + z * 2097152 + (long)bx * 128 * 2048;
  const float* Scb = Sc + z * 32 * 2048;
  float* Cb = Out + z * 2048 * 1024;

  const int t    = threadIdx.x;
  const int lane = t & 63;
  const int wave = t >> 6;
  const int wr   = wave >> 1;
  const int wc   = wave & 1;
  const int arow_l = wr * 64 + (lane & 15);
  const int brow_l = wc * 64 + (lane & 15);
  const int arow_abs = by * 256 + arow_l;         // global S-row of frag base
  const int ck0 = (((lane >> 4)    ) ^ (lane & 7)) * 8;
  const int ck1 = ((4 + (lane >> 4)) ^ (lane & 7)) * 8;

  f32x4 acc[4][4];
  const f32x4 zero = {0.0f, 0.0f, 0.0f, 0.0f};
#pragma unroll
  for (int i = 0; i < 4; ++i)
#pragma unroll
    for (int j = 0; j < 4; ++j) acc[i][j] = zero;

  // scales for iter0 (chunks 0,1) BEFORE stages -> retired by prologue gate
  float scc[2][4];
#pragma unroll
  for (int h = 0; h < 2; ++h)
#pragma unroll
    for (int s = 0; s < 4; ++s)
      scc[h][s] = Scb[(long)h * 2048 + arow_abs + s * 16];

  PROLOGUE_N(2048, 2048);
#pragma unroll 1
  for (int it = 0; it < 15; ++it)
    pv_iter_n<false>(Ab, Bb, lds, acc, it * 128, t, arow_l, brow_l, ck0, ck1,
                     scc, Scb, arow_abs);
  pv_iter_n<true>(Ab, Bb, lds, acc, 1920, t, arow_l, brow_l, ck0, ck1,
                  scc, Scb, arow_abs);

  const int er = (lane >> 4) * 4, ec = lane & 15;
#pragma unroll
  for (int ni = 0; ni < 4; ++ni) {
    const int gcol = bx * 128 + wc * 64 + ni * 16 + ec;
#pragma unroll
    for (int mi = 0; mi < 4; ++mi) {
#pragma unroll
      for (int r = 0; r < 4; ++r) {
        const long grow = (long)by * 256 + wr * 64 + mi * 16 + er + r;
        Cb[grow * 1024 + gcol] = acc[mi][ni][r];
      }
    }
  }
}

// ---------------------------------------------------------------------------
// fp32 -> fp16 elementwise, 8 elems/thread, 16B stores.
// ---------------------------------------------------------------------------
__global__ __launch_bounds__(256)
void cvt_f32_f16_kernel(const float* __restrict__ src, __half* __restrict__ dst, long n)
{
  const long i = ((long)blockIdx.x * 256 + threadIdx.x) * 8;
  if (i + 8 > n) return;
  const float4 a = *(const float4*)(src + i);
  const float4 b = *(const float4*)(src + i + 4);
  f16x8 h;
  h[0] = (_Float16)a.x; h[1] = (_Float16)a.y; h[2] = (_Float16)a.z; h[3] = (_Float16)a.w;
  h[4] = (_Float16)b.x; h[5] = (_Float16)b.y; h[6] = (_Float16)b.z; h[7] = (_Float16)b.w;
  *(f16x8*)((ushort_t*)dst + i) = h;
}

// ---------------------------------------------------------------------------
// Batched weight transpose+convert: dst[z][c][r] = (fp16)srcz[r][c], 1024x1024.
// ---------------------------------------------------------------------------
__global__ __launch_bounds__(256)
void transpose_cvt3_kernel(const float* __restrict__ W0, const float* __restrict__ W1,
                           const float* __restrict__ W2, __half* __restrict__ dst)
{
  __shared__ float tile[32][33];
  const int z = blockIdx.z;
  const float* src = (z == 0) ? W0 : (z == 1) ? W1 : W2;
  __half* d = dst + (long)z * 1024 * 1024;
  const int c0 = blockIdx.x * 32;
  const int r0 = blockIdx.y * 32;
  const int tx = threadIdx.x & 31;
  const int ty = threadIdx.x >> 5;
#pragma unroll
  for (int i = 0; i < 32; i += 8)
    tile[ty + i][tx] = src[(long)(r0 + ty + i) * 1024 + (c0 + tx)];
  __syncthreads();
#pragma unroll
  for (int i = 0; i < 32; i += 8)
    d[(long)(c0 + ty + i) * 1024 + (r0 + tx)] = __float2half(tile[tx][ty + i]);
}

// ---------------------------------------------------------------------------
extern "C" void kernel_launch(void* const* d_in, const int* in_sizes, int n_in,
                              void* d_out, int out_size, void* d_ws, size_t ws_size,
                              hipStream_t stream)
{
  const int  Bb = 4, Nn = 2048, Dd = 1024;
  const long BN = (long)Bb * Nn;  // 8192

  const float* X  = (const float*)d_in[0];
  const float* Wq = (const float*)d_in[1];
  const float* bq = (const float*)d_in[2];
  const float* Wk = (const float*)d_in[3];
  const float* bk = (const float*)d_in[4];
  const float* Wv = (const float*)d_in[5];
  const float* bv = (const float*)d_in[6];
  float* Out      = (float*)d_out;

  uint8_t* w = (uint8_t*)d_ws;
  ushort_t* Wt = (ushort_t*)w;  w += (size_t)3 * Dd * Dd * 2;  // Wq^T|Wk^T|Wv^T fp16

  transpose_cvt3_kernel<<<dim3(Dd / 32, Dd / 32, 3), 256, 0, stream>>>(Wq, Wk, Wv, (__half*)Wt);

  const size_t statsBytes = (size_t)Bb * 32 * Nn * 4;   // 1 MB each
  const size_t fullNeed = (size_t)3 * Dd * Dd * 2       // Wt
                        + 4 * ((size_t)BN * Dd * 2)     // Xh, Q, K, Vt fp16
                        + (size_t)Bb * Nn * Nn * 2      // S fp16
                        + 3 * statsBytes;               // PM, PS, Sc

  if (ws_size >= fullNeed) {
    ushort_t* Xh = (ushort_t*)w;  w += (size_t)BN * Dd * 2;
    ushort_t* Q  = (ushort_t*)w;  w += (size_t)BN * Dd * 2;
    ushort_t* Kb = (ushort_t*)w;  w += (size_t)BN * Dd * 2;
    ushort_t* Vt = (ushort_t*)w;  w += (size_t)BN * Dd * 2;  // [B][Dd][Nn]
    ushort_t* S  = (ushort_t*)w;  w += (size_t)Bb * Nn * Nn * 2;
    float*    PM = (float*)w;     w += statsBytes;
    float*    PS = (float*)w;     w += statsBytes;
    float*    Sc = (float*)w;

    cvt_f32_f16_kernel<<<dim3((unsigned)(BN * Dd / (8 * 256))), 256, 0, stream>>>(
        X, (__half*)Xh, BN * Dd);

    qkv128n_kernel<<<dim3(3 * Dd / 128, BN / 256, 1), 512, 0, stream>>>(
        Xh, Wt, bq, bk, bv, (__half*)Q, (__half*)Kb, Vt);

    qk256_kernel<<<dim3(Nn / 256, Nn / 256, Bb), 512, 0, stream>>>(
        Q, Kb, (__half*)S, PM, PS);

    softmax_reduce_kernel<<<dim3((unsigned)(Bb * Nn / 256)), 256, 0, stream>>>(PM, PS, Sc);

    pv128n_kernel<<<dim3(Dd / 128, Nn / 256, Bb), 512, 0, stream>>>(
        S, Vt, Sc, Out);
  } else {
    // Per-batch fallback (~32 MB ws): same kernels, z-extent 1
    ushort_t* Xh = (ushort_t*)w;  w += (size_t)Nn * Dd * 2;
    ushort_t* Q  = (ushort_t*)w;  w += (size_t)Nn * Dd * 2;
    ushort_t* Kb = (ushort_t*)w;  w += (size_t)Nn * Dd * 2;
    ushort_t* Vt = (ushort_t*)w;  w += (size_t)Nn * Dd * 2;
    ushort_t* S  = (ushort_t*)w;  w += (size_t)Nn * Nn * 2;
    float*    PM = (float*)w;     w += (size_t)32 * Nn * 4;
    float*    PS = (float*)w;     w += (size_t)32 * Nn * 4;
    float*    Sc = (float*)w;

    for (int b = 0; b < Bb; ++b) {
      const float* Xb = X + (long)b * Nn * Dd;
      cvt_f32_f16_kernel<<<dim3((unsigned)((long)Nn * Dd / (8 * 256))), 256, 0, stream>>>(
          Xb, (__half*)Xh, (long)Nn * Dd);
      qkv128n_kernel<<<dim3(3 * Dd / 128, Nn / 256, 1), 512, 0, stream>>>(
          Xh, Wt, bq, bk, bv, (__half*)Q, (__half*)Kb, Vt);
      qk256_kernel<<<dim3(Nn / 256, Nn / 256, 1), 512, 0, stream>>>(
          Q, Kb, (__half*)S, PM, PS);
      softmax_reduce_kernel<<<dim3((unsigned)(Nn / 256)), 256, 0, stream>>>(PM, PS, Sc);
      pv128n_kernel<<<dim3(Dd / 128, Nn / 256, 1), 512, 0, stream>>>(
          S, Vt, Sc, Out + (long)b * Nn * Dd);
    }
  }
}

// Round 4
// 261.147 us; speedup vs baseline: 1.0537x; 1.0235x over previous
//
#include <hip/hip_runtime.h>
#include <hip/hip_bf16.h>
#include <hip/hip_fp16.h>
#include <stdint.h>
#include <math.h>

// ---------------------------------------------------------------------------
// AttentionLayer: Q=XWq+bq, K=XWk+bk, V=XWv+bv; O = softmax(QK^T) V
// B=4, N=2048, D=1024. fp32 I/O; internals fp16, accumulation fp32.
// R10: thick-phase (4-phase/iter, 16 MFMA/phase) 256x128 core for qkv+pv:
//   per 2-K-tile iteration: ph1{rd A0q0,B0q0,B0q1; stage b.B1q1+b.A1q1; MM a(0,*)}
//   ph2{rd A0q1; stage c.A0q0+c.B0q0; MM a(1,*); GATE vmcnt(3)}
//   ph3{rd A1q0,B1q0,B1q1; stage c.B0q1+c.A0q1; MM b(0,*)}
//   ph4{rd A1q1; stage d.A1q0+d.B1q0; MM b(1,*); GATE vmcnt(3)}
//   (halves barrier count + removes redundant B re-read vs R9's 8-phase)
// Launch fusion: prep = transpose_cvt3 + X-cvt in one grid; softmax_reduce
// folded into pv prologue (scales computed into 32KB LDS table). 6->4 launches.
// qk256 kept byte-identical (proven control; 4-phase port next if this wins).
// ---------------------------------------------------------------------------

typedef unsigned short ushort_t;
typedef __attribute__((ext_vector_type(8))) _Float16  f16x8;
typedef __attribute__((ext_vector_type(4))) _Float16  f16x4;
typedef __attribute__((ext_vector_type(4))) float     f32x4;

__device__ __forceinline__ void async_load16(const void* g, void* l) {
  __builtin_amdgcn_global_load_lds(
      (const __attribute__((address_space(1))) void*)g,
      (__attribute__((address_space(3))) void*)l, 16, 0, 0);
}

#define BARR do { __builtin_amdgcn_sched_barrier(0); \
                  __builtin_amdgcn_s_barrier();      \
                  __builtin_amdgcn_sched_barrier(0); } while (0)

// ===========================================================================
// 256x256 8-phase core (qk256 only; unchanged from R8/R9, proven)
// ===========================================================================
#define A0OFF 0
#define B0OFF 16384
#define A1OFF 32768
#define B1OFF 49152

template<int SHIFT>
__device__ __forceinline__ void stage_half(const ushort_t* __restrict__ gb,
                                           int k0, int q, ushort_t* lt, int t)
{
#pragma unroll
  for (int j = 0; j < 2; ++j) {
    const int i   = j * 64 + (t >> 3);
    const int row = ((i >> SHIFT) << (SHIFT + 1)) | (q << SHIFT) | (i & ((1 << SHIFT) - 1));
    const int ch  = (t & 7) ^ (row & 7);
    async_load16(gb + (long)row * 1024 + k0 + ch * 8, lt + row * 64 + (t & 7) * 8);
  }
}

#define RD_A(TP, QM)                                                          \
  do { _Pragma("unroll") for (int m_ = 0; m_ < 4; ++m_) {                     \
    af[m_][0] = *(const f16x8*)&(TP)[(arow0 + (QM)*64 + m_*16) * 64 + ck0];   \
    af[m_][1] = *(const f16x8*)&(TP)[(arow0 + (QM)*64 + m_*16) * 64 + ck1];   \
  } } while (0)

#define RD_B(TP, QN)                                                          \
  do { _Pragma("unroll") for (int n_ = 0; n_ < 2; ++n_) {                     \
    bf[n_][0] = *(const f16x8*)&(TP)[(brow0 + (QN)*32 + n_*16) * 64 + ck0];   \
    bf[n_][1] = *(const f16x8*)&(TP)[(brow0 + (QN)*32 + n_*16) * 64 + ck1];   \
  } } while (0)

#define MM(QM, QN)                                                            \
  do { __builtin_amdgcn_s_setprio(1);                                         \
  _Pragma("unroll") for (int kh_ = 0; kh_ < 2; ++kh_)                         \
    _Pragma("unroll") for (int m_ = 0; m_ < 4; ++m_)                          \
      _Pragma("unroll") for (int n_ = 0; n_ < 2; ++n_)                        \
        acc[(QM)*4+m_][(QN)*2+n_] = __builtin_amdgcn_mfma_f32_16x16x32_f16(   \
            af[m_][kh_], bf[n_][kh_], acc[(QM)*4+m_][(QN)*2+n_], 0, 0, 0);    \
  __builtin_amdgcn_s_setprio(0); } while (0)

template<bool LAST>
__device__ __forceinline__ void iter256(const ushort_t* __restrict__ Ab,
                                        const ushort_t* __restrict__ Bb,
                                        ushort_t* lds, f32x4 (&acc)[8][4],
                                        int ka, int t, int arow0, int brow0,
                                        int ck0, int ck1)
{
  const int kb = ka + 64, kc = ka + 128, kd = ka + 192;
  f16x8 af[4][2], bf[2][2];

  RD_A(lds + A0OFF, 0); RD_B(lds + B0OFF, 0);
  stage_half<5>(Bb, kb, 0, lds + B1OFF, t);
  BARR; MM(0, 0); BARR;

  RD_B(lds + B0OFF, 1);
  if constexpr (!LAST) stage_half<6>(Ab, kc, 0, lds + A0OFF, t);
  BARR; MM(0, 1); BARR;

  RD_A(lds + A0OFF, 1);
  if constexpr (!LAST) stage_half<5>(Bb, kc, 1, lds + B0OFF, t);
  BARR; MM(1, 1); BARR;

  RD_B(lds + B0OFF, 0);
  if constexpr (!LAST) stage_half<6>(Ab, kc, 1, lds + A0OFF, t);
  BARR; MM(1, 0);
  if constexpr (LAST) asm volatile("s_waitcnt vmcnt(0)" ::: "memory");
  else                asm volatile("s_waitcnt vmcnt(6)" ::: "memory");
  BARR;

  RD_A(lds + A1OFF, 0); RD_B(lds + B1OFF, 0);
  if constexpr (!LAST) stage_half<5>(Bb, kc, 0, lds + B0OFF, t);
  BARR; MM(0, 0); BARR;

  RD_B(lds + B1OFF, 1);
  if constexpr (!LAST) stage_half<6>(Ab, kd, 0, lds + A1OFF, t);
  BARR; MM(0, 1); BARR;

  RD_A(lds + A1OFF, 1);
  if constexpr (!LAST) stage_half<5>(Bb, kd, 1, lds + B1OFF, t);
  BARR; MM(1, 1); BARR;

  RD_B(lds + B1OFF, 0);
  if constexpr (!LAST) stage_half<6>(Ab, kd, 1, lds + A1OFF, t);
  BARR; MM(1, 0);
  if constexpr (!LAST) asm volatile("s_waitcnt vmcnt(6)" ::: "memory");
  BARR;
}

__device__ __forceinline__ void gemm256(const ushort_t* __restrict__ Ab,
                                        const ushort_t* __restrict__ Bb,
                                        ushort_t* lds, f32x4 (&acc)[8][4])
{
  const int t    = threadIdx.x;
  const int lane = t & 63;
  const int wave = t >> 6;
  const int wr   = wave >> 2;
  const int wc   = wave & 3;
  const int arow0 = wr * 128 + (lane & 15);
  const int brow0 = wc * 64  + (lane & 15);
  const int ck0 = (((lane >> 4)    ) ^ (lane & 7)) * 8;
  const int ck1 = ((4 + (lane >> 4)) ^ (lane & 7)) * 8;

  stage_half<6>(Ab,  0, 0, lds + A0OFF, t);
  stage_half<5>(Bb,  0, 1, lds + B0OFF, t);
  stage_half<6>(Ab,  0, 1, lds + A0OFF, t);
  stage_half<5>(Bb,  0, 0, lds + B0OFF, t);
  stage_half<6>(Ab, 64, 0, lds + A1OFF, t);
  stage_half<5>(Bb, 64, 1, lds + B1OFF, t);
  stage_half<6>(Ab, 64, 1, lds + A1OFF, t);
  asm volatile("s_waitcnt vmcnt(6)" ::: "memory");
  BARR;

#pragma unroll 1
  for (int it = 0; it < 7; ++it)
    iter256<false>(Ab, Bb, lds, acc, it * 128, t, arow0, brow0, ck0, ck1);
  iter256<true>(Ab, Bb, lds, acc, 896, t, arow0, brow0, ck0, ck1);
}

// ===========================================================================
// 256Mx128N 4-phase core. LDS (ushort): A0 256x64 @0, B0 128x64 @16384,
// A1 @24576, B1 @40960; 96 KB. 8 waves as 4M x 2N, wave output 64x64,
// acc[4][4]. Halves split on row-bit5 (A-half: 2 insts, B-half: 1 inst).
// 4 phases per 2-K-tile iteration, 16 MFMA/phase, gates vmcnt(3).
// ===========================================================================
#define NA0 0
#define NB0 16384
#define NA1 24576
#define NB1 40960

__device__ __forceinline__ void stage_A_n(const ushort_t* __restrict__ gb, long ldk,
                                          int k0, int q, ushort_t* lt, int t)
{
#pragma unroll
  for (int j = 0; j < 2; ++j) {
    const int i   = j * 64 + (t >> 3);                     // 0..127
    const int row = ((i >> 5) << 6) | (q << 5) | (i & 31); // 0..255, bit5==q
    const int ch  = (t & 7) ^ (row & 7);
    async_load16(gb + (long)row * ldk + k0 + ch * 8, lt + row * 64 + (t & 7) * 8);
  }
}

__device__ __forceinline__ void stage_B_n(const ushort_t* __restrict__ gb, long ldk,
                                          int k0, int q, ushort_t* lt, int t)
{
  const int i   = t >> 3;                                  // 0..63
  const int row = ((i >> 5) << 6) | (q << 5) | (i & 31);   // 0..127, bit5==q
  const int ch  = (t & 7) ^ (row & 7);
  async_load16(gb + (long)row * ldk + k0 + ch * 8, lt + row * 64 + (t & 7) * 8);
}

#define RDN_A(TP, QM)                                                         \
  do { _Pragma("unroll") for (int m_ = 0; m_ < 2; ++m_) {                     \
    af[m_][0] = *(const f16x8*)&(TP)[(arow_l + (QM)*32 + m_*16) * 64 + ck0];  \
    af[m_][1] = *(const f16x8*)&(TP)[(arow_l + (QM)*32 + m_*16) * 64 + ck1];  \
  } } while (0)

#define RDN_AS(TP, QM, S)                                                     \
  do { _Pragma("unroll") for (int m_ = 0; m_ < 2; ++m_) {                     \
    af[m_][0] = *(const f16x8*)&(TP)[(arow_l + (QM)*32 + m_*16) * 64 + ck0] * (S)[(QM)*2+m_]; \
    af[m_][1] = *(const f16x8*)&(TP)[(arow_l + (QM)*32 + m_*16) * 64 + ck1] * (S)[(QM)*2+m_]; \
  } } while (0)

#define RDN_B2(TP, QN, BF)                                                    \
  do { _Pragma("unroll") for (int n_ = 0; n_ < 2; ++n_) {                     \
    (BF)[n_][0] = *(const f16x8*)&(TP)[(brow_l + (QN)*32 + n_*16) * 64 + ck0];\
    (BF)[n_][1] = *(const f16x8*)&(TP)[(brow_l + (QN)*32 + n_*16) * 64 + ck1];\
  } } while (0)

// 16 MFMA: A-quadrant QM against both B-quadrants (bq0 -> cols 0-1, bq1 -> 2-3)
#define MM2(QM)                                                               \
  do { __builtin_amdgcn_s_setprio(1);                                         \
  _Pragma("unroll") for (int kh_ = 0; kh_ < 2; ++kh_)                         \
    _Pragma("unroll") for (int m_ = 0; m_ < 2; ++m_)                          \
      _Pragma("unroll") for (int n_ = 0; n_ < 2; ++n_) {                      \
        acc[(QM)*2+m_][n_]   = __builtin_amdgcn_mfma_f32_16x16x32_f16(        \
            af[m_][kh_], bq0[n_][kh_], acc[(QM)*2+m_][n_], 0, 0, 0);          \
        acc[(QM)*2+m_][2+n_] = __builtin_amdgcn_mfma_f32_16x16x32_f16(        \
            af[m_][kh_], bq1[n_][kh_], acc[(QM)*2+m_][2+n_], 0, 0, 0);        \
      }                                                                       \
  __builtin_amdgcn_s_setprio(0); } while (0)

// Gate ledger (steady state): enter iter with 3 outstanding (b.A1q0,b.B1q0).
// ph1 +3 (b.B1q1,b.A1q1) -> 6; ph2 +3 (c.A0q0,c.B0q0) -> 9, vmcnt(3) retires
// all 6 of tile b; ph3 +3 (c.B0q1,c.A0q1) -> 6; ph4 +3 (d.A1q0,d.B1q0) -> 9,
// vmcnt(3) retires all 6 of tile c. WAR: every restage >=1 barrier after its
// region's last read (verified per-region).
template<bool LAST>
__device__ __forceinline__ void iter4_n(const ushort_t* __restrict__ Ab,
                                        const ushort_t* __restrict__ Bb,
                                        long lda, long ldb,
                                        ushort_t* lds, f32x4 (&acc)[4][4],
                                        int ka, int t, int arow_l, int brow_l,
                                        int ck0, int ck1)
{
  const int kb = ka + 64, kc = ka + 128, kd = ka + 192;
  f16x8 af[2][2], bq0[2][2], bq1[2][2];

  // ph1: tile a quads (0,*); complete tile b staging
  RDN_A(lds + NA0, 0);
  RDN_B2(lds + NB0, 0, bq0);
  RDN_B2(lds + NB0, 1, bq1);
  stage_B_n(Bb, ldb, kb, 1, lds + NB1, t);
  stage_A_n(Ab, lda, kb, 1, lds + NA1, t);
  BARR; MM2(0); BARR;

  // ph2: tile a quads (1,*); stage c.A0q0 + c.B0q0; GATE
  RDN_A(lds + NA0, 1);
  if constexpr (!LAST) {
    stage_A_n(Ab, lda, kc, 0, lds + NA0, t);
    stage_B_n(Bb, ldb, kc, 0, lds + NB0, t);
  }
  BARR; MM2(1);
  if constexpr (LAST) asm volatile("s_waitcnt vmcnt(0)" ::: "memory");
  else                asm volatile("s_waitcnt vmcnt(3)" ::: "memory");
  BARR;

  // ph3: tile b quads (0,*); stage c.B0q1 + c.A0q1
  RDN_A(lds + NA1, 0);
  RDN_B2(lds + NB1, 0, bq0);
  RDN_B2(lds + NB1, 1, bq1);
  if constexpr (!LAST) {
    stage_B_n(Bb, ldb, kc, 1, lds + NB0, t);
    stage_A_n(Ab, lda, kc, 1, lds + NA0, t);
  }
  BARR; MM2(0); BARR;

  // ph4: tile b quads (1,*); stage d.A1q0 + d.B1q0; GATE
  RDN_A(lds + NA1, 1);
  if constexpr (!LAST) {
    stage_A_n(Ab, lda, kd, 0, lds + NA1, t);
    stage_B_n(Bb, ldb, kd, 0, lds + NB1, t);
  }
  BARR; MM2(1);
  if constexpr (!LAST) asm volatile("s_waitcnt vmcnt(3)" ::: "memory");
  BARR;
}

// PV variant: per-64-chunk row scales read from LDS table ScL[32][256]
// (pure ds_reads -> the vmcnt gate stream stays stage-only).
template<bool LAST>
__device__ __forceinline__ void pv_iter4(const ushort_t* __restrict__ Ab,
                                         const ushort_t* __restrict__ Bb,
                                         ushort_t* lds, const float (*ScL)[256],
                                         f32x4 (&acc)[4][4],
                                         int ka, int t, int arow_l, int brow_l,
                                         int ck0, int ck1)
{
  const int kb = ka + 64, kc = ka + 128, kd = ka + 192;
  const int cba = ka >> 6;
  f16x8 af[2][2], bq0[2][2], bq1[2][2];
  _Float16 sa[4], sb[4];
#pragma unroll
  for (int s = 0; s < 4; ++s) {
    sa[s] = (_Float16)ScL[cba][arow_l + s * 16];
    sb[s] = (_Float16)ScL[cba + 1][arow_l + s * 16];
  }

  RDN_AS(lds + NA0, 0, sa);
  RDN_B2(lds + NB0, 0, bq0);
  RDN_B2(lds + NB0, 1, bq1);
  stage_B_n(Bb, 2048, kb, 1, lds + NB1, t);
  stage_A_n(Ab, 2048, kb, 1, lds + NA1, t);
  BARR; MM2(0); BARR;

  RDN_AS(lds + NA0, 1, sa);
  if constexpr (!LAST) {
    stage_A_n(Ab, 2048, kc, 0, lds + NA0, t);
    stage_B_n(Bb, 2048, kc, 0, lds + NB0, t);
  }
  BARR; MM2(1);
  if constexpr (LAST) asm volatile("s_waitcnt vmcnt(0)" ::: "memory");
  else                asm volatile("s_waitcnt vmcnt(3)" ::: "memory");
  BARR;

  RDN_AS(lds + NA1, 0, sb);
  RDN_B2(lds + NB1, 0, bq0);
  RDN_B2(lds + NB1, 1, bq1);
  if constexpr (!LAST) {
    stage_B_n(Bb, 2048, kc, 1, lds + NB0, t);
    stage_A_n(Ab, 2048, kc, 1, lds + NA0, t);
  }
  BARR; MM2(0); BARR;

  RDN_AS(lds + NA1, 1, sb);
  if constexpr (!LAST) {
    stage_A_n(Ab, 2048, kd, 0, lds + NA1, t);
    stage_B_n(Bb, 2048, kd, 0, lds + NB1, t);
  }
  BARR; MM2(1);
  if constexpr (!LAST) asm volatile("s_waitcnt vmcnt(3)" ::: "memory");
  BARR;
}

// Prologue: tile a fully (6 insts) + b.{A1q0,B1q0} (3) -> vmcnt(3) keeps b's 3.
#define PROLOGUE4(LDA, LDB)                                 \
  do {                                                      \
    stage_A_n(Ab, (LDA),  0, 0, lds + NA0, t);              \
    stage_B_n(Bb, (LDB),  0, 0, lds + NB0, t);              \
    stage_B_n(Bb, (LDB),  0, 1, lds + NB0, t);              \
    stage_A_n(Ab, (LDA),  0, 1, lds + NA0, t);              \
    stage_A_n(Ab, (LDA), 64, 0, lds + NA1, t);              \
    stage_B_n(Bb, (LDB), 64, 0, lds + NB1, t);              \
    asm volatile("s_waitcnt vmcnt(3)" ::: "memory");        \
    BARR;                                                   \
  } while (0)

// ---------------------------------------------------------------------------
// Fused QKV projection on the 4-phase 256x128 core. A = Xh [8192][1024],
// BT = Wt [3072][1024]. grid (24, M/256) = 768 blocks = 3 full rounds.
// ---------------------------------------------------------------------------
__global__ __launch_bounds__(512, 2)
void qkv4_kernel(const ushort_t* __restrict__ A, const ushort_t* __restrict__ BT,
                 const float* __restrict__ bq, const float* __restrict__ bk,
                 const float* __restrict__ bvp,
                 __half* __restrict__ Qh, __half* __restrict__ Kh,
                 ushort_t* __restrict__ Vt)
{
  __shared__ __align__(16) ushort_t lds[49152];   // 96 KB

  const int nb = gridDim.x * gridDim.y;           // %8==0
  int id = blockIdx.y * gridDim.x + blockIdx.x;
  id = (id & 7) * (nb >> 3) + (id >> 3);          // bijective XCD swizzle
  const int bx = id % gridDim.x;                  // 0..23 (N-tile of 128)
  const int by = id / gridDim.x;                  // M-tile of 256

  const ushort_t* Ab = A  + (long)by * 256 * 1024;
  const ushort_t* Bb = BT + (long)bx * 128 * 1024;

  const int t    = threadIdx.x;
  const int lane = t & 63;
  const int wave = t >> 6;
  const int wr   = wave >> 1;                     // 0..3 (M, 64 rows)
  const int wc   = wave & 1;                      // 0..1 (N, 64 cols)
  const int arow_l = wr * 64 + (lane & 15);
  const int brow_l = wc * 64 + (lane & 15);
  const int ck0 = (((lane >> 4)    ) ^ (lane & 7)) * 8;
  const int ck1 = ((4 + (lane >> 4)) ^ (lane & 7)) * 8;

  f32x4 acc[4][4];
  const f32x4 zero = {0.0f, 0.0f, 0.0f, 0.0f};
#pragma unroll
  for (int i = 0; i < 4; ++i)
#pragma unroll
    for (int j = 0; j < 4; ++j) acc[i][j] = zero;

  PROLOGUE4(1024, 1024);
#pragma unroll 1
  for (int it = 0; it < 7; ++it)
    iter4_n<false>(Ab, Bb, 1024, 1024, lds, acc, it * 128, t, arow_l, brow_l, ck0, ck1);
  iter4_n<true>(Ab, Bb, 1024, 1024, lds, acc, 896, t, arow_l, brow_l, ck0, ck1);

  const int er = (lane >> 4) * 4, ec = lane & 15;
  const int tgt = bx >> 3;                        // 0:Q 1:K 2:V (uniform)
  const float* bias = (tgt == 0) ? bq : (tgt == 1) ? bk : bvp;

#pragma unroll
  for (int ni = 0; ni < 4; ++ni) {
    const int col = (bx & 7) * 128 + wc * 64 + ni * 16 + ec;   // 0..1023
    const float bval = bias[col];
#pragma unroll
    for (int mi = 0; mi < 4; ++mi) {
      const long grow0 = (long)by * 256 + wr * 64 + mi * 16 + er;
      if (tgt < 2) {
        __half* o = (tgt == 0) ? Qh : Kh;
#pragma unroll
        for (int r = 0; r < 4; ++r)
          o[(grow0 + r) * 1024 + col] = __float2half(acc[mi][ni][r] + bval);
      } else {
        const long b  = grow0 >> 11;              // batch
        const long ml = grow0 & 2047;             // aligned to 4
        f16x4 v4;
#pragma unroll
        for (int r = 0; r < 4; ++r) v4[r] = (_Float16)(acc[mi][ni][r] + bval);
        *(f16x4*)&Vt[b * 2097152 + (long)col * 2048 + ml] = v4;
      }
    }
  }
}

// ---------------------------------------------------------------------------
// QK^T on the 256x256 8-phase core (unchanged - control). grid (8, 8, B).
// ---------------------------------------------------------------------------
__global__ __launch_bounds__(512, 2)
void qk256_kernel(const ushort_t* __restrict__ Q, const ushort_t* __restrict__ Kh,
                  __half* __restrict__ S, float* __restrict__ PM, float* __restrict__ PS)
{
  __shared__ __align__(16) ushort_t lds[65536];

  const int nb = gridDim.x * gridDim.y;
  int id = blockIdx.y * gridDim.x + blockIdx.x;
  id = (id & 7) * (nb >> 3) + (id >> 3);
  const int bx = id % gridDim.x;
  const int by = id / gridDim.x;
  const long z = blockIdx.z;

  const ushort_t* Ab = Q  + z * 2048 * 1024 + (long)by * 256 * 1024;
  const ushort_t* Bb = Kh + z * 2048 * 1024 + (long)bx * 256 * 1024;
  __half* Sb = S + z * 2048 * 2048;

  f32x4 acc[8][4];
  const f32x4 zero = {0.0f, 0.0f, 0.0f, 0.0f};
#pragma unroll
  for (int i = 0; i < 8; ++i)
#pragma unroll
    for (int j = 0; j < 4; ++j) acc[i][j] = zero;

  gemm256(Ab, Bb, lds, acc);

  const int t = threadIdx.x, lane = t & 63, wave = t >> 6;
  const int wr = wave >> 2, wc = wave & 3;
  const int er = (lane >> 4) * 4, ec = lane & 15;
  const int cc = bx * 4 + wc;                     // 0..31
  float* PMb = PM + z * 32 * 2048 + (long)cc * 2048;
  float* PSb = PS + z * 32 * 2048 + (long)cc * 2048;

#pragma unroll
  for (int m8 = 0; m8 < 8; ++m8)
#pragma unroll
    for (int r = 0; r < 4; ++r) {
      float m = fmaxf(fmaxf(acc[m8][0][r], acc[m8][1][r]),
                      fmaxf(acc[m8][2][r], acc[m8][3][r]));
      m = fmaxf(m, __shfl_xor(m, 1));
      m = fmaxf(m, __shfl_xor(m, 2));
      m = fmaxf(m, __shfl_xor(m, 4));
      m = fmaxf(m, __shfl_xor(m, 8));
      float s = 0.0f;
#pragma unroll
      for (int n4 = 0; n4 < 4; ++n4) {
        const float e = __expf(acc[m8][n4][r] - m);
        acc[m8][n4][r] = e;
        s += e;
      }
      s += __shfl_xor(s, 1);
      s += __shfl_xor(s, 2);
      s += __shfl_xor(s, 4);
      s += __shfl_xor(s, 8);
      if (ec == 0) {
        const long row = (long)by * 256 + wr * 128 + m8 * 16 + er + r;
        PMb[row] = m;
        PSb[row] = s;
      }
    }

#pragma unroll
  for (int n4 = 0; n4 < 4; ++n4) {
    const long col = (long)bx * 256 + wc * 64 + n4 * 16 + ec;
#pragma unroll
    for (int m8 = 0; m8 < 8; ++m8)
#pragma unroll
      for (int r = 0; r < 4; ++r) {
        const long grow = (long)by * 256 + wr * 128 + m8 * 16 + er + r;
        Sb[grow * 2048 + col] = __float2half(acc[m8][n4][r]);
      }
  }
}

// ---------------------------------------------------------------------------
// PV on the 4-phase core, softmax-reduce fused into the prologue:
// ScL[cb][row_local] = exp(PM[cb][row]-m)/l computed per block (its 256 rows).
// Out[m][e] = sum_k (S[m][k]*ScL[k>>6][m]) * Vt[e][k]. grid (8, 8, 4). K=2048.
// ---------------------------------------------------------------------------
__global__ __launch_bounds__(512, 2)
void pv4_kernel(const ushort_t* __restrict__ S, const ushort_t* __restrict__ Vt,
                const float* __restrict__ PM, const float* __restrict__ PS,
                float* __restrict__ Out)
{
  __shared__ __align__(16) ushort_t lds[49152];   // 96 KB
  __shared__ float ScL[32][256];                  // +32 KB = 128 KB total

  const int nb = gridDim.x * gridDim.y;           // %8==0
  int id = blockIdx.y * gridDim.x + blockIdx.x;
  id = (id & 7) * (nb >> 3) + (id >> 3);
  const int bx = id % gridDim.x;                  // N-tile (Out cols / Vt rows)
  const int by = id / gridDim.x;                  // M-tile (S rows)
  const long z = blockIdx.z;

  const ushort_t* Ab = S  + z * 4194304 + (long)by * 256 * 2048;
  const ushort_t* Bb = Vt + z * 2097152 + (long)bx * 128 * 2048;
  float* Cb = Out + z * 2048 * 1024;

  const int t = threadIdx.x;

  // ---- fused softmax reduce: scales for this block's 256 rows ----
  if (t < 256) {
    const long row = (long)by * 256 + t;
    const float* PMb = PM + z * 32 * 2048;
    const float* PSb = PS + z * 32 * 2048;
    float pm[32];
    float m = -3.4e38f;
#pragma unroll
    for (int cb = 0; cb < 32; ++cb) {
      pm[cb] = PMb[(long)cb * 2048 + row];
      m = fmaxf(m, pm[cb]);
    }
    float l = 0.0f;
#pragma unroll
    for (int cb = 0; cb < 32; ++cb)
      l += PSb[(long)cb * 2048 + row] * __expf(pm[cb] - m);
    const float inv = 1.0f / l;
#pragma unroll
    for (int cb = 0; cb < 32; ++cb)
      ScL[cb][t] = __expf(pm[cb] - m) * inv;
  }
  __syncthreads();   // full drain: ScL visible; vmcnt back to 0 before staging

  const int lane = t & 63;
  const int wave = t >> 6;
  const int wr   = wave >> 1;
  const int wc   = wave & 1;
  const int arow_l = wr * 64 + (lane & 15);
  const int brow_l = wc * 64 + (lane & 15);
  const int ck0 = (((lane >> 4)    ) ^ (lane & 7)) * 8;
  const int ck1 = ((4 + (lane >> 4)) ^ (lane & 7)) * 8;

  f32x4 acc[4][4];
  const f32x4 zero = {0.0f, 0.0f, 0.0f, 0.0f};
#pragma unroll
  for (int i = 0; i < 4; ++i)
#pragma unroll
    for (int j = 0; j < 4; ++j) acc[i][j] = zero;

  PROLOGUE4(2048, 2048);
#pragma unroll 1
  for (int it = 0; it < 15; ++it)
    pv_iter4<false>(Ab, Bb, lds, ScL, acc, it * 128, t, arow_l, brow_l, ck0, ck1);
  pv_iter4<true>(Ab, Bb, lds, ScL, acc, 1920, t, arow_l, brow_l, ck0, ck1);

  const int er = (lane >> 4) * 4, ec = lane & 15;
#pragma unroll
  for (int ni = 0; ni < 4; ++ni) {
    const int gcol = bx * 128 + wc * 64 + ni * 16 + ec;
#pragma unroll
    for (int mi = 0; mi < 4; ++mi) {
#pragma unroll
      for (int r = 0; r < 4; ++r) {
        const long grow = (long)by * 256 + wr * 64 + mi * 16 + er + r;
        Cb[grow * 1024 + gcol] = acc[mi][ni][r];
      }
    }
  }
}

// ---------------------------------------------------------------------------
// Fused prep: z<3 -> weight transpose+cvt (dst[z][c][r] = fp16 srcz[r][c]);
// z>=3 -> X fp32->fp16 slice. grid (32, 32, 7), 256 thr.
// ---------------------------------------------------------------------------
__global__ __launch_bounds__(256)
void prep_kernel(const float* __restrict__ W0, const float* __restrict__ W1,
                 const float* __restrict__ W2, __half* __restrict__ dstW,
                 const float* __restrict__ X, __half* __restrict__ Xh)
{
  __shared__ float tile[32][33];
  const int z = blockIdx.z;
  if (z < 3) {
    const float* src = (z == 0) ? W0 : (z == 1) ? W1 : W2;
    __half* d = dstW + (long)z * 1024 * 1024;
    const int c0 = blockIdx.x * 32;
    const int r0 = blockIdx.y * 32;
    const int tx = threadIdx.x & 31;
    const int ty = threadIdx.x >> 5;
#pragma unroll
    for (int i = 0; i < 32; i += 8)
      tile[ty + i][tx] = src[(long)(r0 + ty + i) * 1024 + (c0 + tx)];
    __syncthreads();
#pragma unroll
    for (int i = 0; i < 32; i += 8)
      d[(long)(c0 + ty + i) * 1024 + (r0 + tx)] = __float2half(tile[tx][ty + i]);
  } else {
    const int bid = blockIdx.y * gridDim.x + blockIdx.x;        // 0..1023
    const long i = (((long)(z - 3) * 1024 + bid) * 256 + threadIdx.x) * 8;
    const float4 a = *(const float4*)(X + i);
    const float4 b = *(const float4*)(X + i + 4);
    f16x8 h;
    h[0] = (_Float16)a.x; h[1] = (_Float16)a.y; h[2] = (_Float16)a.z; h[3] = (_Float16)a.w;
    h[4] = (_Float16)b.x; h[5] = (_Float16)b.y; h[6] = (_Float16)b.z; h[7] = (_Float16)b.w;
    *(f16x8*)((ushort_t*)Xh + i) = h;
  }
}

// ---------------------------------------------------------------------------
// Standalone cvt + transpose (fallback path only).
// ---------------------------------------------------------------------------
__global__ __launch_bounds__(256)
void cvt_f32_f16_kernel(const float* __restrict__ src, __half* __restrict__ dst, long n)
{
  const long i = ((long)blockIdx.x * 256 + threadIdx.x) * 8;
  if (i + 8 > n) return;
  const float4 a = *(const float4*)(src + i);
  const float4 b = *(const float4*)(src + i + 4);
  f16x8 h;
  h[0] = (_Float16)a.x; h[1] = (_Float16)a.y; h[2] = (_Float16)a.z; h[3] = (_Float16)a.w;
  h[4] = (_Float16)b.x; h[5] = (_Float16)b.y; h[6] = (_Float16)b.z; h[7] = (_Float16)b.w;
  *(f16x8*)((ushort_t*)dst + i) = h;
}

__global__ __launch_bounds__(256)
void transpose_cvt3_kernel(const float* __restrict__ W0, const float* __restrict__ W1,
                           const float* __restrict__ W2, __half* __restrict__ dst)
{
  __shared__ float tile[32][33];
  const int z = blockIdx.z;
  const float* src = (z == 0) ? W0 : (z == 1) ? W1 : W2;
  __half* d = dst + (long)z * 1024 * 1024;
  const int c0 = blockIdx.x * 32;
  const int r0 = blockIdx.y * 32;
  const int tx = threadIdx.x & 31;
  const int ty = threadIdx.x >> 5;
#pragma unroll
  for (int i = 0; i < 32; i += 8)
    tile[ty + i][tx] = src[(long)(r0 + ty + i) * 1024 + (c0 + tx)];
  __syncthreads();
#pragma unroll
  for (int i = 0; i < 32; i += 8)
    d[(long)(c0 + ty + i) * 1024 + (r0 + tx)] = __float2half(tile[tx][ty + i]);
}

// ---------------------------------------------------------------------------
extern "C" void kernel_launch(void* const* d_in, const int* in_sizes, int n_in,
                              void* d_out, int out_size, void* d_ws, size_t ws_size,
                              hipStream_t stream)
{
  const int  Bb = 4, Nn = 2048, Dd = 1024;
  const long BN = (long)Bb * Nn;  // 8192

  const float* X  = (const float*)d_in[0];
  const float* Wq = (const float*)d_in[1];
  const float* bq = (const float*)d_in[2];
  const float* Wk = (const float*)d_in[3];
  const float* bk = (const float*)d_in[4];
  const float* Wv = (const float*)d_in[5];
  const float* bv = (const float*)d_in[6];
  float* Out      = (float*)d_out;

  uint8_t* w = (uint8_t*)d_ws;
  ushort_t* Wt = (ushort_t*)w;  w += (size_t)3 * Dd * Dd * 2;  // Wq^T|Wk^T|Wv^T fp16

  const size_t statsBytes = (size_t)Bb * 32 * Nn * 4;   // 1 MB each
  const size_t fullNeed = (size_t)3 * Dd * Dd * 2       // Wt
                        + 4 * ((size_t)BN * Dd * 2)     // Xh, Q, K, Vt fp16
                        + (size_t)Bb * Nn * Nn * 2      // S fp16
                        + 2 * statsBytes;               // PM, PS

  if (ws_size >= fullNeed) {
    ushort_t* Xh = (ushort_t*)w;  w += (size_t)BN * Dd * 2;
    ushort_t* Q  = (ushort_t*)w;  w += (size_t)BN * Dd * 2;
    ushort_t* Kb = (ushort_t*)w;  w += (size_t)BN * Dd * 2;
    ushort_t* Vt = (ushort_t*)w;  w += (size_t)BN * Dd * 2;  // [B][Dd][Nn]
    ushort_t* S  = (ushort_t*)w;  w += (size_t)Bb * Nn * Nn * 2;
    float*    PM = (float*)w;     w += statsBytes;
    float*    PS = (float*)w;

    prep_kernel<<<dim3(32, 32, 7), 256, 0, stream>>>(Wq, Wk, Wv, (__half*)Wt, X, (__half*)Xh);

    qkv4_kernel<<<dim3(3 * Dd / 128, BN / 256, 1), 512, 0, stream>>>(
        Xh, Wt, bq, bk, bv, (__half*)Q, (__half*)Kb, Vt);

    qk256_kernel<<<dim3(Nn / 256, Nn / 256, Bb), 512, 0, stream>>>(
        Q, Kb, (__half*)S, PM, PS);

    pv4_kernel<<<dim3(Dd / 128, Nn / 256, Bb), 512, 0, stream>>>(
        S, Vt, PM, PS, Out);
  } else {
    // Per-batch fallback (~32 MB ws): same cores, z-extent 1
    ushort_t* Xh = (ushort_t*)w;  w += (size_t)Nn * Dd * 2;
    ushort_t* Q  = (ushort_t*)w;  w += (size_t)Nn * Dd * 2;
    ushort_t* Kb = (ushort_t*)w;  w += (size_t)Nn * Dd * 2;
    ushort_t* Vt = (ushort_t*)w;  w += (size_t)Nn * Dd * 2;
    ushort_t* S  = (ushort_t*)w;  w += (size_t)Nn * Nn * 2;
    float*    PM = (float*)w;     w += (size_t)32 * Nn * 4;
    float*    PS = (float*)w;

    transpose_cvt3_kernel<<<dim3(Dd / 32, Dd / 32, 3), 256, 0, stream>>>(Wq, Wk, Wv, (__half*)Wt);

    for (int b = 0; b < Bb; ++b) {
      const float* Xb = X + (long)b * Nn * Dd;
      cvt_f32_f16_kernel<<<dim3((unsigned)((long)Nn * Dd / (8 * 256))), 256, 0, stream>>>(
          Xb, (__half*)Xh, (long)Nn * Dd);
      qkv4_kernel<<<dim3(3 * Dd / 128, Nn / 256, 1), 512, 0, stream>>>(
          Xh, Wt, bq, bk, bv, (__half*)Q, (__half*)Kb, Vt);
      qk256_kernel<<<dim3(Nn / 256, Nn / 256, 1), 512, 0, stream>>>(
          Q, Kb, (__half*)S, PM, PS);
      pv4_kernel<<<dim3(Dd / 128, Nn / 256, 1), 512, 0, stream>>>(
          S, Vt, PM, PS, Out + (long)b * Nn * Dd);
    }
  }
}

// Round 5
// 245.318 us; speedup vs baseline: 1.1217x; 1.0645x over previous
//
#include <hip/hip_runtime.h>
#include <hip/hip_bf16.h>
#include <hip/hip_fp16.h>
#include <stdint.h>
#include <math.h>

// ---------------------------------------------------------------------------
// AttentionLayer: Q=XWq+bq, K=XWk+bk, V=XWv+bv; O = softmax(QK^T) V
// B=4, N=2048, D=1024. fp32 I/O; internals fp16, accumulation fp32.
// R11: read-ahead (RA) 256x128 core. R10 proved phases serialize LDS reads
// and MFMA (measured 3350 cyc/K-tile = 1540 LDS + 1240 MFMA + drain). RA
// issues phase p+1's ds_reads before phase p's MFMA into a second register
// set -> LDS pipe drains under the MFMA window; per-phase cost -> max not sum.
//   ph1: RD a.q1->aG | stage c.A0q0+B0q0 | BARR | MM(aF,bF,q0) | vmcnt(3) | BARR
//   ph2: RD b.q0->aF, b.B->bG | stage c.A0q1+B0q1 | BARR | MM(aG,bF,q1) | BARR
//   ph3: RD b.q1->aG | stage d.A1q0+B1q0 | BARR | MM(aF,bG,q0) | vmcnt(3) | BARR
//   ph4: RD c.q0->aF, c.B->bF | stage d.A1q1+B1q1 | BARR | MM(aG,bG,q1) | BARR
// Gates verified: ph1 gate retires tile b's 6 stages (read ph2); ph3 gate
// retires tile c's 6 (read ph4). All WAR pairs >=1 barrier. qkv/qk/pv all on
// this core; qk grid (16,8,4)=512=2 rounds, chunk cc=bx*2+wc.
// ---------------------------------------------------------------------------

typedef unsigned short ushort_t;
typedef __attribute__((ext_vector_type(8))) _Float16  f16x8;
typedef __attribute__((ext_vector_type(4))) _Float16  f16x4;
typedef __attribute__((ext_vector_type(4))) float     f32x4;

__device__ __forceinline__ void async_load16(const void* g, void* l) {
  __builtin_amdgcn_global_load_lds(
      (const __attribute__((address_space(1))) void*)g,
      (__attribute__((address_space(3))) void*)l, 16, 0, 0);
}

#define BARR do { __builtin_amdgcn_sched_barrier(0); \
                  __builtin_amdgcn_s_barrier();      \
                  __builtin_amdgcn_sched_barrier(0); } while (0)

// LDS layout (ushort units): A0 256x64 @0, B0 128x64 @16384, A1 @24576,
// B1 @40960; total 49152 ushorts = 96 KB.
#define NA0 0
#define NB0 16384
#define NA1 24576
#define NB1 40960

// Stage A-half (128 rows of the 256-row A region, split on row-bit5): 2 insts.
__device__ __forceinline__ void stage_A_n(const ushort_t* __restrict__ gb, long ldk,
                                          int k0, int q, ushort_t* lt, int t)
{
#pragma unroll
  for (int j = 0; j < 2; ++j) {
    const int i   = j * 64 + (t >> 3);                     // 0..127
    const int row = ((i >> 5) << 6) | (q << 5) | (i & 31); // 0..255, bit5==q
    const int ch  = (t & 7) ^ (row & 7);
    async_load16(gb + (long)row * ldk + k0 + ch * 8, lt + row * 64 + (t & 7) * 8);
  }
}

// Stage B-half (64 rows of the 128-row B region, split on row-bit5): 1 inst.
__device__ __forceinline__ void stage_B_n(const ushort_t* __restrict__ gb, long ldk,
                                          int k0, int q, ushort_t* lt, int t)
{
  const int i   = t >> 3;                                  // 0..63
  const int row = ((i >> 5) << 6) | (q << 5) | (i & 31);   // 0..127, bit5==q
  const int ch  = (t & 7) ^ (row & 7);
  async_load16(gb + (long)row * ldk + k0 + ch * 8, lt + row * 64 + (t & 7) * 8);
}

// Fragment reads (swizzled ck0/ck1 from scope). All indices compile-time.
#define RD_A4(SET, BASE, QM)                                                  \
  do { _Pragma("unroll") for (int m_ = 0; m_ < 2; ++m_) {                     \
    SET[m_][0] = *(const f16x8*)&lds[(BASE) + (arow_l + (QM)*32 + m_*16) * 64 + ck0]; \
    SET[m_][1] = *(const f16x8*)&lds[(BASE) + (arow_l + (QM)*32 + m_*16) * 64 + ck1]; \
  } } while (0)

#define RD_B4(SET, BASE)                                                      \
  do { _Pragma("unroll") for (int q_ = 0; q_ < 2; ++q_)                       \
    _Pragma("unroll") for (int n_ = 0; n_ < 2; ++n_) {                        \
      SET[q_][n_][0] = *(const f16x8*)&lds[(BASE) + (brow_l + q_*32 + n_*16) * 64 + ck0]; \
      SET[q_][n_][1] = *(const f16x8*)&lds[(BASE) + (brow_l + q_*32 + n_*16) * 64 + ck1]; \
    } } while (0)

// 16 MFMA: A-quadrant QM x both B-quadrants.
#define MM16(AS, BS, QM)                                                      \
  do { __builtin_amdgcn_s_setprio(1);                                         \
  _Pragma("unroll") for (int kh_ = 0; kh_ < 2; ++kh_)                         \
    _Pragma("unroll") for (int m_ = 0; m_ < 2; ++m_)                          \
      _Pragma("unroll") for (int n_ = 0; n_ < 2; ++n_) {                      \
        acc[(QM)*2+m_][n_]   = __builtin_amdgcn_mfma_f32_16x16x32_f16(        \
            AS[m_][kh_], BS[0][n_][kh_], acc[(QM)*2+m_][n_], 0, 0, 0);        \
        acc[(QM)*2+m_][2+n_] = __builtin_amdgcn_mfma_f32_16x16x32_f16(        \
            AS[m_][kh_], BS[1][n_][kh_], acc[(QM)*2+m_][2+n_], 0, 0, 0);      \
      }                                                                       \
  __builtin_amdgcn_s_setprio(0); } while (0)

// PV: scale applied at MFMA time (temp reg) so the lgkm wait for the scale
// load lands inside the MFMA phase, not the read-issue slot.
#define MM16S(AS, BS, QM, SC)                                                 \
  do { __builtin_amdgcn_s_setprio(1);                                         \
  _Pragma("unroll") for (int m_ = 0; m_ < 2; ++m_)                            \
    _Pragma("unroll") for (int kh_ = 0; kh_ < 2; ++kh_) {                     \
      const f16x8 as_ = AS[m_][kh_] * (_Float16)(SC)[(QM)*2+m_];              \
      _Pragma("unroll") for (int n_ = 0; n_ < 2; ++n_) {                      \
        acc[(QM)*2+m_][n_]   = __builtin_amdgcn_mfma_f32_16x16x32_f16(        \
            as_, BS[0][n_][kh_], acc[(QM)*2+m_][n_], 0, 0, 0);                \
        acc[(QM)*2+m_][2+n_] = __builtin_amdgcn_mfma_f32_16x16x32_f16(        \
            as_, BS[1][n_][kh_], acc[(QM)*2+m_][2+n_], 0, 0, 0);              \
      } }                                                                     \
  __builtin_amdgcn_s_setprio(0); } while (0)

// One iteration = 2 K-tiles (a=ka buf0, b=ka+64 buf1); stages c=ka+128,
// d=ka+192. Reads one phase ahead of their MFMA. Gates vmcnt(3) @ ph1/ph3.
template<bool LAST>
__device__ __forceinline__ void iterRA(const ushort_t* __restrict__ Ab,
                                       const ushort_t* __restrict__ Bb,
                                       long lda, long ldb,
                                       ushort_t* lds, f32x4 (&acc)[4][4],
                                       int ka, int t, int arow_l, int brow_l,
                                       int ck0, int ck1,
                                       f16x8 (&aF)[2][2], f16x8 (&aG)[2][2],
                                       f16x8 (&bF)[2][2][2], f16x8 (&bG)[2][2][2])
{
  const int kc = ka + 128, kd = ka + 192;

  // ph1
  RD_A4(aG, NA0, 1);
  if constexpr (!LAST) { stage_A_n(Ab, lda, kc, 0, lds + NA0, t);
                         stage_B_n(Bb, ldb, kc, 0, lds + NB0, t); }
  BARR;
  MM16(aF, bF, 0);
  if constexpr (LAST) asm volatile("s_waitcnt vmcnt(0)" ::: "memory");
  else                asm volatile("s_waitcnt vmcnt(3)" ::: "memory");
  BARR;
  // ph2
  RD_A4(aF, NA1, 0);
  RD_B4(bG, NB1);
  if constexpr (!LAST) { stage_A_n(Ab, lda, kc, 1, lds + NA0, t);
                         stage_B_n(Bb, ldb, kc, 1, lds + NB0, t); }
  BARR;
  MM16(aG, bF, 1);
  BARR;
  // ph3
  RD_A4(aG, NA1, 1);
  if constexpr (!LAST) { stage_A_n(Ab, lda, kd, 0, lds + NA1, t);
                         stage_B_n(Bb, ldb, kd, 0, lds + NB1, t); }
  BARR;
  MM16(aF, bG, 0);
  if constexpr (!LAST) asm volatile("s_waitcnt vmcnt(3)" ::: "memory");
  BARR;
  // ph4
  if constexpr (!LAST) {
    RD_A4(aF, NA0, 0);
    RD_B4(bF, NB0);
    stage_A_n(Ab, lda, kd, 1, lds + NA1, t);
    stage_B_n(Bb, ldb, kd, 1, lds + NB1, t);
  }
  BARR;
  MM16(aG, bG, 1);
  BARR;
}

template<bool LAST>
__device__ __forceinline__ void pv_iterRA(const ushort_t* __restrict__ Ab,
                                          const ushort_t* __restrict__ Bb,
                                          ushort_t* lds, const float (*ScL)[256],
                                          f32x4 (&acc)[4][4],
                                          int ka, int t, int arow_l, int brow_l,
                                          int ck0, int ck1,
                                          f16x8 (&aF)[2][2], f16x8 (&aG)[2][2],
                                          f16x8 (&bF)[2][2][2], f16x8 (&bG)[2][2][2])
{
  const int kc = ka + 128, kd = ka + 192;
  const int cba = ka >> 6;
  float sa4[4], sb4[4];
#pragma unroll
  for (int s = 0; s < 4; ++s) {
    sa4[s] = ScL[cba][arow_l + s * 16];
    sb4[s] = ScL[cba + 1][arow_l + s * 16];
  }

  // ph1
  RD_A4(aG, NA0, 1);
  if constexpr (!LAST) { stage_A_n(Ab, 2048, kc, 0, lds + NA0, t);
                         stage_B_n(Bb, 2048, kc, 0, lds + NB0, t); }
  BARR;
  MM16S(aF, bF, 0, sa4);
  if constexpr (LAST) asm volatile("s_waitcnt vmcnt(0)" ::: "memory");
  else                asm volatile("s_waitcnt vmcnt(3)" ::: "memory");
  BARR;
  // ph2
  RD_A4(aF, NA1, 0);
  RD_B4(bG, NB1);
  if constexpr (!LAST) { stage_A_n(Ab, 2048, kc, 1, lds + NA0, t);
                         stage_B_n(Bb, 2048, kc, 1, lds + NB0, t); }
  BARR;
  MM16S(aG, bF, 1, sa4);
  BARR;
  // ph3
  RD_A4(aG, NA1, 1);
  if constexpr (!LAST) { stage_A_n(Ab, 2048, kd, 0, lds + NA1, t);
                         stage_B_n(Bb, 2048, kd, 0, lds + NB1, t); }
  BARR;
  MM16S(aF, bG, 0, sb4);
  if constexpr (!LAST) asm volatile("s_waitcnt vmcnt(3)" ::: "memory");
  BARR;
  // ph4
  if constexpr (!LAST) {
    RD_A4(aF, NA0, 0);
    RD_B4(bF, NB0);
    stage_A_n(Ab, 2048, kd, 1, lds + NA1, t);
    stage_B_n(Bb, 2048, kd, 1, lds + NB1, t);
  }
  BARR;
  MM16S(aG, bG, 1, sb4);
  BARR;
}

// Prologue: stage a(6); vmcnt(0); BARR; RD a.q0+a.B (prev-ph4 role);
// stage b(6) [prev ph3+ph4 roles]; BARR. Outstanding at ph1 entry = b's 6.
#define PROLOGUE_RA(LDA, LDB)                               \
  do {                                                      \
    stage_A_n(Ab, (LDA),  0, 0, lds + NA0, t);              \
    stage_B_n(Bb, (LDB),  0, 0, lds + NB0, t);              \
    stage_A_n(Ab, (LDA),  0, 1, lds + NA0, t);              \
    stage_B_n(Bb, (LDB),  0, 1, lds + NB0, t);              \
    asm volatile("s_waitcnt vmcnt(0)" ::: "memory");        \
    BARR;                                                   \
    RD_A4(aF, NA0, 0);                                      \
    RD_B4(bF, NB0);                                         \
    stage_A_n(Ab, (LDA), 64, 0, lds + NA1, t);              \
    stage_B_n(Bb, (LDB), 64, 0, lds + NB1, t);              \
    stage_A_n(Ab, (LDA), 64, 1, lds + NA1, t);              \
    stage_B_n(Bb, (LDB), 64, 1, lds + NB1, t);              \
    BARR;                                                   \
  } while (0)

// ---------------------------------------------------------------------------
// Fused QKV projection. A = Xh [8192][1024], BT = Wt [3072][1024].
// grid (24, 32) = 768 blocks = 3 full rounds.
// ---------------------------------------------------------------------------
__global__ __launch_bounds__(512, 2)
void qkv_ra_kernel(const ushort_t* __restrict__ A, const ushort_t* __restrict__ BT,
                   const float* __restrict__ bq, const float* __restrict__ bk,
                   const float* __restrict__ bvp,
                   __half* __restrict__ Qh, __half* __restrict__ Kh,
                   ushort_t* __restrict__ Vt)
{
  __shared__ __align__(16) ushort_t lds[49152];   // 96 KB

  const int nb = gridDim.x * gridDim.y;           // %8==0
  int id = blockIdx.y * gridDim.x + blockIdx.x;
  id = (id & 7) * (nb >> 3) + (id >> 3);          // bijective XCD swizzle
  const int bx = id % gridDim.x;                  // 0..23 (N-tile of 128)
  const int by = id / gridDim.x;                  // M-tile of 256

  const ushort_t* Ab = A  + (long)by * 256 * 1024;
  const ushort_t* Bb = BT + (long)bx * 128 * 1024;

  const int t    = threadIdx.x;
  const int lane = t & 63;
  const int wave = t >> 6;
  const int wr   = wave >> 1;                     // 0..3 (M, 64 rows)
  const int wc   = wave & 1;                      // 0..1 (N, 64 cols)
  const int arow_l = wr * 64 + (lane & 15);
  const int brow_l = wc * 64 + (lane & 15);
  const int ck0 = (((lane >> 4)    ) ^ (lane & 7)) * 8;
  const int ck1 = ((4 + (lane >> 4)) ^ (lane & 7)) * 8;

  f32x4 acc[4][4];
  const f32x4 zero = {0.0f, 0.0f, 0.0f, 0.0f};
#pragma unroll
  for (int i = 0; i < 4; ++i)
#pragma unroll
    for (int j = 0; j < 4; ++j) acc[i][j] = zero;

  f16x8 aF[2][2], aG[2][2], bF[2][2][2], bG[2][2][2];

  PROLOGUE_RA(1024, 1024);
#pragma unroll 1
  for (int it = 0; it < 7; ++it)
    iterRA<false>(Ab, Bb, 1024, 1024, lds, acc, it * 128, t, arow_l, brow_l,
                  ck0, ck1, aF, aG, bF, bG);
  iterRA<true>(Ab, Bb, 1024, 1024, lds, acc, 896, t, arow_l, brow_l,
               ck0, ck1, aF, aG, bF, bG);

  const int er = (lane >> 4) * 4, ec = lane & 15;
  const int tgt = bx >> 3;                        // 0:Q 1:K 2:V (uniform)
  const float* bias = (tgt == 0) ? bq : (tgt == 1) ? bk : bvp;

#pragma unroll
  for (int ni = 0; ni < 4; ++ni) {
    const int col = (bx & 7) * 128 + wc * 64 + ni * 16 + ec;   // 0..1023
    const float bval = bias[col];
#pragma unroll
    for (int mi = 0; mi < 4; ++mi) {
      const long grow0 = (long)by * 256 + wr * 64 + mi * 16 + er;
      if (tgt < 2) {
        __half* o = (tgt == 0) ? Qh : Kh;
#pragma unroll
        for (int r = 0; r < 4; ++r)
          o[(grow0 + r) * 1024 + col] = __float2half(acc[mi][ni][r] + bval);
      } else {
        const long b  = grow0 >> 11;              // batch
        const long ml = grow0 & 2047;             // aligned to 4
        f16x4 v4;
#pragma unroll
        for (int r = 0; r < 4; ++r) v4[r] = (_Float16)(acc[mi][ni][r] + bval);
        *(f16x4*)&Vt[b * 2097152 + (long)col * 2048 + ml] = v4;
      }
    }
  }
}

// ---------------------------------------------------------------------------
// QK^T on the RA core with fused partial softmax, 64-col chunks.
// Wave (wr,wc): 64x64 tile; chunk cc = bx*2+wc (0..31). grid (16, 8, 4).
// ---------------------------------------------------------------------------
__global__ __launch_bounds__(512, 2)
void qk_ra_kernel(const ushort_t* __restrict__ Q, const ushort_t* __restrict__ Kh,
                  __half* __restrict__ S, float* __restrict__ PM, float* __restrict__ PS)
{
  __shared__ __align__(16) ushort_t lds[49152];

  const int nb = gridDim.x * gridDim.y;           // 128, %8==0
  int id = blockIdx.y * gridDim.x + blockIdx.x;
  id = (id & 7) * (nb >> 3) + (id >> 3);
  const int bx = id % gridDim.x;                  // 0..15 (K-tile of 128)
  const int by = id / gridDim.x;                  // 0..7  (Q-tile of 256)
  const long z = blockIdx.z;

  const ushort_t* Ab = Q  + z * 2048 * 1024 + (long)by * 256 * 1024;
  const ushort_t* Bb = Kh + z * 2048 * 1024 + (long)bx * 128 * 1024;
  __half* Sb = S + z * 2048 * 2048;

  const int t    = threadIdx.x;
  const int lane = t & 63;
  const int wave = t >> 6;
  const int wr   = wave >> 1;
  const int wc   = wave & 1;
  const int arow_l = wr * 64 + (lane & 15);
  const int brow_l = wc * 64 + (lane & 15);
  const int ck0 = (((lane >> 4)    ) ^ (lane & 7)) * 8;
  const int ck1 = ((4 + (lane >> 4)) ^ (lane & 7)) * 8;

  f32x4 acc[4][4];
  const f32x4 zero = {0.0f, 0.0f, 0.0f, 0.0f};
#pragma unroll
  for (int i = 0; i < 4; ++i)
#pragma unroll
    for (int j = 0; j < 4; ++j) acc[i][j] = zero;

  f16x8 aF[2][2], aG[2][2], bF[2][2][2], bG[2][2][2];

  PROLOGUE_RA(1024, 1024);
#pragma unroll 1
  for (int it = 0; it < 7; ++it)
    iterRA<false>(Ab, Bb, 1024, 1024, lds, acc, it * 128, t, arow_l, brow_l,
                  ck0, ck1, aF, aG, bF, bG);
  iterRA<true>(Ab, Bb, 1024, 1024, lds, acc, 896, t, arow_l, brow_l,
               ck0, ck1, aF, aG, bF, bG);

  const int er = (lane >> 4) * 4, ec = lane & 15;
  const int cc = bx * 2 + wc;                     // 0..31
  float* PMb = PM + z * 32 * 2048 + (long)cc * 2048;
  float* PSb = PS + z * 32 * 2048 + (long)cc * 2048;

#pragma unroll
  for (int mi = 0; mi < 4; ++mi)
#pragma unroll
    for (int r = 0; r < 4; ++r) {
      float m = fmaxf(fmaxf(acc[mi][0][r], acc[mi][1][r]),
                      fmaxf(acc[mi][2][r], acc[mi][3][r]));
      m = fmaxf(m, __shfl_xor(m, 1));   // reduce over the 16 ec lanes
      m = fmaxf(m, __shfl_xor(m, 2));
      m = fmaxf(m, __shfl_xor(m, 4));
      m = fmaxf(m, __shfl_xor(m, 8));
      float s = 0.0f;
#pragma unroll
      for (int ni = 0; ni < 4; ++ni) {
        const float e = __expf(acc[mi][ni][r] - m);
        acc[mi][ni][r] = e;
        s += e;
      }
      s += __shfl_xor(s, 1);
      s += __shfl_xor(s, 2);
      s += __shfl_xor(s, 4);
      s += __shfl_xor(s, 8);
      if (ec == 0) {
        const long row = (long)by * 256 + wr * 64 + mi * 16 + er + r;
        PMb[row] = m;
        PSb[row] = s;
      }
    }

  // store p_unnorm = exp(s - m_chunk) fp16
#pragma unroll
  for (int ni = 0; ni < 4; ++ni) {
    const long col = (long)bx * 128 + wc * 64 + ni * 16 + ec;
#pragma unroll
    for (int mi = 0; mi < 4; ++mi)
#pragma unroll
      for (int r = 0; r < 4; ++r) {
        const long grow = (long)by * 256 + wr * 64 + mi * 16 + er + r;
        Sb[grow * 2048 + col] = __float2half(acc[mi][ni][r]);
      }
  }
}

// ---------------------------------------------------------------------------
// PV on the RA core, softmax-reduce fused into the prologue:
// ScL[cb][row_local] = exp(PM[cb][row]-m)/l for this block's 256 rows.
// Out[m][e] = sum_k (S[m][k]*ScL[k>>6][m]) * Vt[e][k]. grid (8, 8, 4). K=2048.
// ---------------------------------------------------------------------------
__global__ __launch_bounds__(512, 2)
void pv_ra_kernel(const ushort_t* __restrict__ S, const ushort_t* __restrict__ Vt,
                  const float* __restrict__ PM, const float* __restrict__ PS,
                  float* __restrict__ Out)
{
  __shared__ __align__(16) ushort_t lds[49152];   // 96 KB
  __shared__ float ScL[32][256];                  // +32 KB = 128 KB

  const int nb = gridDim.x * gridDim.y;           // 64, %8==0
  int id = blockIdx.y * gridDim.x + blockIdx.x;
  id = (id & 7) * (nb >> 3) + (id >> 3);
  const int bx = id % gridDim.x;                  // N-tile (Out cols / Vt rows)
  const int by = id / gridDim.x;                  // M-tile (S rows)
  const long z = blockIdx.z;

  const ushort_t* Ab = S  + z * 4194304 + (long)by * 256 * 2048;
  const ushort_t* Bb = Vt + z * 2097152 + (long)bx * 128 * 2048;
  float* Cb = Out + z * 2048 * 1024;

  const int t = threadIdx.x;

  // ---- fused softmax reduce for this block's 256 rows ----
  if (t < 256) {
    const long row = (long)by * 256 + t;
    const float* PMb = PM + z * 32 * 2048;
    const float* PSb = PS + z * 32 * 2048;
    float pm[32];
    float m = -3.4e38f;
#pragma unroll
    for (int cb = 0; cb < 32; ++cb) {
      pm[cb] = PMb[(long)cb * 2048 + row];
      m = fmaxf(m, pm[cb]);
    }
    float l = 0.0f;
#pragma unroll
    for (int cb = 0; cb < 32; ++cb)
      l += PSb[(long)cb * 2048 + row] * __expf(pm[cb] - m);
    const float inv = 1.0f / l;
#pragma unroll
    for (int cb = 0; cb < 32; ++cb)
      ScL[cb][t] = __expf(pm[cb] - m) * inv;
  }
  __syncthreads();   // full drain; ScL visible; vmcnt clean before staging

  const int lane = t & 63;
  const int wave = t >> 6;
  const int wr   = wave >> 1;
  const int wc   = wave & 1;
  const int arow_l = wr * 64 + (lane & 15);
  const int brow_l = wc * 64 + (lane & 15);
  const int ck0 = (((lane >> 4)    ) ^ (lane & 7)) * 8;
  const int ck1 = ((4 + (lane >> 4)) ^ (lane & 7)) * 8;

  f32x4 acc[4][4];
  const f32x4 zero = {0.0f, 0.0f, 0.0f, 0.0f};
#pragma unroll
  for (int i = 0; i < 4; ++i)
#pragma unroll
    for (int j = 0; j < 4; ++j) acc[i][j] = zero;

  f16x8 aF[2][2], aG[2][2], bF[2][2][2], bG[2][2][2];

  PROLOGUE_RA(2048, 2048);
#pragma unroll 1
  for (int it = 0; it < 15; ++it)
    pv_iterRA<false>(Ab, Bb, lds, ScL, acc, it * 128, t, arow_l, brow_l,
                     ck0, ck1, aF, aG, bF, bG);
  pv_iterRA<true>(Ab, Bb, lds, ScL, acc, 1920, t, arow_l, brow_l,
                  ck0, ck1, aF, aG, bF, bG);

  const int er = (lane >> 4) * 4, ec = lane & 15;
#pragma unroll
  for (int ni = 0; ni < 4; ++ni) {
    const int gcol = bx * 128 + wc * 64 + ni * 16 + ec;
#pragma unroll
    for (int mi = 0; mi < 4; ++mi) {
#pragma unroll
      for (int r = 0; r < 4; ++r) {
        const long grow = (long)by * 256 + wr * 64 + mi * 16 + er + r;
        Cb[grow * 1024 + gcol] = acc[mi][ni][r];
      }
    }
  }
}

// ---------------------------------------------------------------------------
// Fused prep: z<3 -> weight transpose+cvt; z>=3 -> X fp32->fp16 slice.
// grid (32, 32, 7), 256 thr.
// ---------------------------------------------------------------------------
__global__ __launch_bounds__(256)
void prep_kernel(const float* __restrict__ W0, const float* __restrict__ W1,
                 const float* __restrict__ W2, __half* __restrict__ dstW,
                 const float* __restrict__ X, __half* __restrict__ Xh)
{
  __shared__ float tile[32][33];
  const int z = blockIdx.z;
  if (z < 3) {
    const float* src = (z == 0) ? W0 : (z == 1) ? W1 : W2;
    __half* d = dstW + (long)z * 1024 * 1024;
    const int c0 = blockIdx.x * 32;
    const int r0 = blockIdx.y * 32;
    const int tx = threadIdx.x & 31;
    const int ty = threadIdx.x >> 5;
#pragma unroll
    for (int i = 0; i < 32; i += 8)
      tile[ty + i][tx] = src[(long)(r0 + ty + i) * 1024 + (c0 + tx)];
    __syncthreads();
#pragma unroll
    for (int i = 0; i < 32; i += 8)
      d[(long)(c0 + ty + i) * 1024 + (r0 + tx)] = __float2half(tile[tx][ty + i]);
  } else {
    const int bid = blockIdx.y * gridDim.x + blockIdx.x;        // 0..1023
    const long i = (((long)(z - 3) * 1024 + bid) * 256 + threadIdx.x) * 8;
    const float4 a = *(const float4*)(X + i);
    const float4 b = *(const float4*)(X + i + 4);
    f16x8 h;
    h[0] = (_Float16)a.x; h[1] = (_Float16)a.y; h[2] = (_Float16)a.z; h[3] = (_Float16)a.w;
    h[4] = (_Float16)b.x; h[5] = (_Float16)b.y; h[6] = (_Float16)b.z; h[7] = (_Float16)b.w;
    *(f16x8*)((ushort_t*)Xh + i) = h;
  }
}

// ---------------------------------------------------------------------------
// Standalone cvt + transpose (fallback path only).
// ---------------------------------------------------------------------------
__global__ __launch_bounds__(256)
void cvt_f32_f16_kernel(const float* __restrict__ src, __half* __restrict__ dst, long n)
{
  const long i = ((long)blockIdx.x * 256 + threadIdx.x) * 8;
  if (i + 8 > n) return;
  const float4 a = *(const float4*)(src + i);
  const float4 b = *(const float4*)(src + i + 4);
  f16x8 h;
  h[0] = (_Float16)a.x; h[1] = (_Float16)a.y; h[2] = (_Float16)a.z; h[3] = (_Float16)a.w;
  h[4] = (_Float16)b.x; h[5] = (_Float16)b.y; h[6] = (_Float16)b.z; h[7] = (_Float16)b.w;
  *(f16x8*)((ushort_t*)dst + i) = h;
}

__global__ __launch_bounds__(256)
void transpose_cvt3_kernel(const float* __restrict__ W0, const float* __restrict__ W1,
                           const float* __restrict__ W2, __half* __restrict__ dst)
{
  __shared__ float tile[32][33];
  const int z = blockIdx.z;
  const float* src = (z == 0) ? W0 : (z == 1) ? W1 : W2;
  __half* d = dst + (long)z * 1024 * 1024;
  const int c0 = blockIdx.x * 32;
  const int r0 = blockIdx.y * 32;
  const int tx = threadIdx.x & 31;
  const int ty = threadIdx.x >> 5;
#pragma unroll
  for (int i = 0; i < 32; i += 8)
    tile[ty + i][tx] = src[(long)(r0 + ty + i) * 1024 + (c0 + tx)];
  __syncthreads();
#pragma unroll
  for (int i = 0; i < 32; i += 8)
    d[(long)(c0 + ty + i) * 1024 + (r0 + tx)] = __float2half(tile[tx][ty + i]);
}

// ---------------------------------------------------------------------------
extern "C" void kernel_launch(void* const* d_in, const int* in_sizes, int n_in,
                              void* d_out, int out_size, void* d_ws, size_t ws_size,
                              hipStream_t stream)
{
  const int  Bb = 4, Nn = 2048, Dd = 1024;
  const long BN = (long)Bb * Nn;  // 8192

  const float* X  = (const float*)d_in[0];
  const float* Wq = (const float*)d_in[1];
  const float* bq = (const float*)d_in[2];
  const float* Wk = (const float*)d_in[3];
  const float* bk = (const float*)d_in[4];
  const float* Wv = (const float*)d_in[5];
  const float* bv = (const float*)d_in[6];
  float* Out      = (float*)d_out;

  uint8_t* w = (uint8_t*)d_ws;
  ushort_t* Wt = (ushort_t*)w;  w += (size_t)3 * Dd * Dd * 2;  // Wq^T|Wk^T|Wv^T fp16

  const size_t statsBytes = (size_t)Bb * 32 * Nn * 4;   // 1 MB each
  const size_t fullNeed = (size_t)3 * Dd * Dd * 2       // Wt
                        + 4 * ((size_t)BN * Dd * 2)     // Xh, Q, K, Vt fp16
                        + (size_t)Bb * Nn * Nn * 2      // S fp16
                        + 2 * statsBytes;               // PM, PS

  if (ws_size >= fullNeed) {
    ushort_t* Xh = (ushort_t*)w;  w += (size_t)BN * Dd * 2;
    ushort_t* Q  = (ushort_t*)w;  w += (size_t)BN * Dd * 2;
    ushort_t* Kb = (ushort_t*)w;  w += (size_t)BN * Dd * 2;
    ushort_t* Vt = (ushort_t*)w;  w += (size_t)BN * Dd * 2;  // [B][Dd][Nn]
    ushort_t* S  = (ushort_t*)w;  w += (size_t)Bb * Nn * Nn * 2;
    float*    PM = (float*)w;     w += statsBytes;
    float*    PS = (float*)w;

    prep_kernel<<<dim3(32, 32, 7), 256, 0, stream>>>(Wq, Wk, Wv, (__half*)Wt, X, (__half*)Xh);

    qkv_ra_kernel<<<dim3(3 * Dd / 128, BN / 256, 1), 512, 0, stream>>>(
        Xh, Wt, bq, bk, bv, (__half*)Q, (__half*)Kb, Vt);

    qk_ra_kernel<<<dim3(Nn / 128, Nn / 256, Bb), 512, 0, stream>>>(
        Q, Kb, (__half*)S, PM, PS);

    pv_ra_kernel<<<dim3(Dd / 128, Nn / 256, Bb), 512, 0, stream>>>(
        S, Vt, PM, PS, Out);
  } else {
    // Per-batch fallback (~32 MB ws): same cores, z-extent 1
    ushort_t* Xh = (ushort_t*)w;  w += (size_t)Nn * Dd * 2;
    ushort_t* Q  = (ushort_t*)w;  w += (size_t)Nn * Dd * 2;
    ushort_t* Kb = (ushort_t*)w;  w += (size_t)Nn * Dd * 2;
    ushort_t* Vt = (ushort_t*)w;  w += (size_t)Nn * Dd * 2;
    ushort_t* S  = (ushort_t*)w;  w += (size_t)Nn * Nn * 2;
    float*    PM = (float*)w;     w += (size_t)32 * Nn * 4;
    float*    PS = (float*)w;

    transpose_cvt3_kernel<<<dim3(Dd / 32, Dd / 32, 3), 256, 0, stream>>>(Wq, Wk, Wv, (__half*)Wt);

    for (int b = 0; b < Bb; ++b) {
      const float* Xb = X + (long)b * Nn * Dd;
      cvt_f32_f16_kernel<<<dim3((unsigned)((long)Nn * Dd / (8 * 256))), 256, 0, stream>>>(
          Xb, (__half*)Xh, (long)Nn * Dd);
      qkv_ra_kernel<<<dim3(3 * Dd / 128, Nn / 256, 1), 512, 0, stream>>>(
          Xh, Wt, bq, bk, bv, (__half*)Q, (__half*)Kb, Vt);
      qk_ra_kernel<<<dim3(Nn / 128, Nn / 256, 1), 512, 0, stream>>>(
          Q, Kb, (__half*)S, PM, PS);
      pv_ra_kernel<<<dim3(Dd / 128, Nn / 256, 1), 512, 0, stream>>>(
          S, Vt, PM, PS, Out + (long)b * Nn * Dd);
    }
  }
}